// Round 1
// baseline (3700.700 us; speedup 1.0000x reference)
//
#include <hip/hip_runtime.h>
#include <math.h>

#define NPART 8192
#define NBHX  64
#define EPX   300000
#define EBX   160000
#define FOUR_OVER_PI 1.27323954473516f

__device__ __forceinline__ float signf(float x){ return (x>0.f)?1.f:((x<0.f)?-1.f:0.f); }

// ---------------- feats build ----------------
__global__ void feats_kernel(const float* __restrict__ vel, const float* __restrict__ mass,
                             const float* __restrict__ bhvel, const float* __restrict__ bhmass,
                             float* __restrict__ feats, float* __restrict__ bhfeats) {
  int i = blockIdx.x*256 + threadIdx.x;
  if (i < NPART) {
    feats[i*4+0]=vel[i*3+0]; feats[i*4+1]=vel[i*3+1]; feats[i*4+2]=vel[i*3+2]; feats[i*4+3]=mass[i];
  }
  if (i < NBHX) {
    bhfeats[i*4+0]=bhvel[i*3+0]; bhfeats[i*4+1]=bhvel[i*3+1]; bhfeats[i*4+2]=bhvel[i*3+2]; bhfeats[i*4+3]=bhmass[i];
  }
}

// ---------------- edge geometry ----------------
// per edge: src, base corner index (i0x*16+i0y*4+i0z), 8 weights = win*wx*wy*wz
__global__ void geom_kernel(const float* __restrict__ ppos, const float* __restrict__ qpos,
                            const int* __restrict__ src, const int* __restrict__ dst,
                            int E, int n_out, float inv_radius,
                            int* __restrict__ gsrc, int* __restrict__ gbase, float* __restrict__ gw) {
  int e = blockIdx.x*256 + threadIdx.x;
  if (e >= E) return;
  int s = src[e], t = dst[e];
  gsrc[e] = s;
  if (t >= n_out) { // padding edge, never referenced via CSR, store zeros
    gbase[e] = 0;
    for (int j=0;j<8;j++) gw[(size_t)e*8+j] = 0.f;
    return;
  }
  float x = (ppos[s*3+0] - qpos[t*3+0]) * inv_radius;
  float y = (ppos[s*3+1] - qpos[t*3+1]) * inv_radius;
  float z = (ppos[s*3+2] - qpos[t*3+2]) * inv_radius;
  float r2 = x*x + y*y + z*z;
  float w1 = 1.f - r2;
  float win = fminf(fmaxf(w1*w1*w1, 0.f), 1.f);
  // ball -> cube (volume preserving)
  const float eps = 1e-8f;
  float sq = r2;
  float nrm = sqrtf(sq);
  float xy = x*x + y*y;
  bool caps = (1.25f*z*z > xy);
  float s_caps = sqrtf(3.f*nrm/(nrm + fabsf(z) + eps));
  float s_side = nrm / sqrtf(xy + eps);
  float sc = caps ? s_caps : s_side;
  bool valid = sq > eps;
  float cx = valid ? x*sc : 0.f;
  float cy = valid ? y*sc : 0.f;
  float cz = valid ? (caps ? signf(z)*nrm : 1.5f*z) : 0.f;
  float rxy = sqrtf(cx*cx + cy*cy);
  bool regA = (cx*cx >= cy*cy);
  float safe_cx = (fabsf(cx) > eps) ? cx : 1.0f;
  float safe_cy = (fabsf(cy) > eps) ? cy : 1.0f;
  float uA = signf(cx)*rxy;
  float vA = uA * FOUR_OVER_PI * atanf(cy/safe_cx);
  float vB = signf(cy)*rxy;
  float uB = vB * FOUR_OVER_PI * atanf(cx/safe_cy);
  bool okxy = rxy > eps;
  float u = okxy ? (regA ? uA : uB) : 0.f;
  float v = okxy ? (regA ? vA : vB) : 0.f;
  // trilinear setup, K=4, align_corners: t = (u+1)*1.5
  float tt[3] = { (u+1.f)*1.5f, (v+1.f)*1.5f, (cz+1.f)*1.5f };
  int i0[3]; float f[3];
#pragma unroll
  for (int ax=0; ax<3; ax++) {
    float tf = floorf(tt[ax]);
    tf = fminf(fmaxf(tf, 0.f), 2.f);
    i0[ax] = (int)tf;
    f[ax] = tt[ax] - tf;
  }
  gbase[e] = (i0[0]*4 + i0[1])*4 + i0[2];
#pragma unroll
  for (int j=0;j<8;j++) {
    float wx = (j&4) ? f[0] : 1.f - f[0];
    float wy = (j&2) ? f[1] : 1.f - f[1];
    float wz = (j&1) ? f[2] : 1.f - f[2];
    gw[(size_t)e*8+j] = win * wx * wy * wz;
  }
}

// ---------------- CSR row offsets (dst is sorted non-decreasing) ----------------
__global__ void csr_kernel(const int* __restrict__ dst, int E, int* __restrict__ rs) {
  int n = blockIdx.x*256 + threadIdx.x;
  if (n > NPART) return;
  int lo = 0, hi = E;
  while (lo < hi) { int mid = (lo+hi)>>1; if (dst[mid] < n) lo = mid+1; else hi = mid; }
  rs[n] = lo;
}

// ---------------- scatter: per-node T row accumulation in LDS ----------------
template<int CIN>
__global__ __launch_bounds__(256) void scatter_kernel(
    const int* __restrict__ rs, const int* __restrict__ gsrc, const int* __restrict__ gbase,
    const float* __restrict__ gw, const float* __restrict__ feats,
    float* __restrict__ T, int m0) {
  int node = m0 + blockIdx.x;
  __shared__ float Tl[64*CIN];
  __shared__ int s_src[8], s_base[8];
  __shared__ float s_w[8][8];
  for (int i = threadIdx.x; i < 64*CIN; i += 256) Tl[i] = 0.f;
  int e0 = rs[node], e1 = rs[node+1];
  __syncthreads();
  for (int eb = e0; eb < e1; eb += 8) {
    int ne = min(8, e1 - eb);
    int t = threadIdx.x;
    if (t < 80) {
      int e = t/10, fld = t - e*10;
      if (e < ne) {
        if (fld == 0) s_src[e] = gsrc[eb+e];
        else if (fld == 1) s_base[e] = gbase[eb+e];
        else s_w[e][fld-2] = gw[(size_t)(eb+e)*8 + (fld-2)];
      }
    }
    __syncthreads();
    int total = ne*8*CIN;
    for (int it = threadIdx.x; it < total; it += 256) {
      int e = it / (8*CIN);
      int r = it - e*(8*CIN);
      int j = r / CIN;
      int c = r - j*CIN;
      float v = s_w[e][j] * feats[(size_t)s_src[e]*CIN + c];
      int k = s_base[e] + ((j>>2)&1)*16 + ((j>>1)&1)*4 + (j&1);
      atomicAdd(&Tl[k*CIN + c], v);
    }
    __syncthreads();
  }
  for (int i = threadIdx.x; i < 64*CIN; i += 256)
    T[(size_t)blockIdx.x*(64*CIN) + i] = Tl[i];
}

// ---------------- tiled f32 GEMM: out[m, d] = T[m, :KC] . W[:, d] + b[d] ----------------
template<int COUT>
__global__ __launch_bounds__(256) void gemm_kernel(
    const float* __restrict__ T, int KC, const float* __restrict__ W,
    const float* __restrict__ b, float* __restrict__ out,
    int ldo, int coff, int m0, int relu) {
  constexpr int BM = 32, BK = 32;
  constexpr int NG = 256 / COUT;     // row groups
  constexpr int RPT = BM / NG;       // rows per thread
  __shared__ float Tt[BM*BK];
  __shared__ float Wt[BK*COUT];
  int d = threadIdx.x % COUT;
  int rg = threadIdx.x / COUT;
  float acc[RPT];
#pragma unroll
  for (int i=0;i<RPT;i++) acc[i] = 0.f;
  const float* Trow = T + (size_t)blockIdx.x*BM*KC;
  for (int k0 = 0; k0 < KC; k0 += BK) {
    { // stage T tile: 1024 floats, each thread one float4
      int idx = threadIdx.x*4;
      int r = idx / BK, cc = idx % BK;
      *(float4*)(Tt + idx) = *(const float4*)(Trow + (size_t)r*KC + k0 + cc);
    }
    for (int i = threadIdx.x*4; i < BK*COUT; i += 1024) { // stage W tile
      int r = i / COUT, cc = i % COUT;
      *(float4*)(Wt + i) = *(const float4*)(W + (size_t)(k0+r)*COUT + cc);
    }
    __syncthreads();
#pragma unroll 8
    for (int k2 = 0; k2 < BK; k2++) {
      float wv = Wt[k2*COUT + d];
#pragma unroll
      for (int i=0;i<RPT;i++) acc[i] += Tt[(rg + NG*i)*BK + k2] * wv;
    }
    __syncthreads();
  }
  float bb = b[d];
#pragma unroll
  for (int i=0;i<RPT;i++) {
    float v = acc[i] + bb;
    if (relu) v = fmaxf(v, 0.f);
    int row = m0 + blockIdx.x*BM + rg + NG*i;
    out[(size_t)row*ldo + coff + d] = v;
  }
}

// ---------------- final conv layer, COUT=3, naive ----------------
__global__ void conv3_kernel(const float* __restrict__ T, int KC, const float* __restrict__ W,
                             const float* __restrict__ b, float* __restrict__ out, int m0, int cn) {
  int idx = blockIdx.x*256 + threadIdx.x;
  int n = idx/3, d = idx - n*3;
  if (n >= cn) return;
  const float* Trow = T + (size_t)n*KC;
  float acc = b[d];
  for (int k=0;k<KC;k++) acc += Trow[k]*W[k*3+d];
  out[(size_t)(m0+n)*3 + d] = acc;
}

// ---------------- dense (1x1) layers ----------------
template<int CIN, int COUT, int RELU, int ACCUM, int ADDSKIP>
__global__ void dense_kernel(const float* __restrict__ X, const float* __restrict__ Wd,
                             const float* __restrict__ bd, float* __restrict__ out,
                             int ldo, int coff, const float* __restrict__ skip) {
  int idx = blockIdx.x*256 + threadIdx.x;
  if (idx >= NPART*COUT) return;
  int n = idx / COUT, d = idx - n*COUT;
  float acc = bd[d];
  const float* x = X + (size_t)n*CIN;
#pragma unroll 4
  for (int c=0;c<CIN;c++) acc += x[c]*Wd[c*COUT + d];
  if (RELU) acc = fmaxf(acc, 0.f);
  if (ADDSKIP) acc += skip[(size_t)n*COUT + d];
  float* o = out + (size_t)n*ldo + coff + d;
  if (ACCUM) *o += acc; else *o = acc;
}

extern "C" void kernel_launch(void* const* d_in, const int* in_sizes, int n_in,
                              void* d_out, int out_size, void* d_ws, size_t ws_size,
                              hipStream_t stream) {
  const float* pos    = (const float*)d_in[0];
  const float* vel    = (const float*)d_in[1];
  const float* mass   = (const float*)d_in[2];
  const float* bh_pos = (const float*)d_in[3];
  const float* bh_vel = (const float*)d_in[4];
  const float* bh_mass= (const float*)d_in[5];
  const int* pp_src   = (const int*)d_in[6];
  const int* pp_dst   = (const int*)d_in[7];
  const int* bh_src   = (const int*)d_in[8];
  const int* bh_dst   = (const int*)d_in[9];
  const float* W0a=(const float*)d_in[10]; const float* b0a=(const float*)d_in[11];
  const float* Wd0=(const float*)d_in[12]; const float* bd0=(const float*)d_in[13];
  const float* W0b=(const float*)d_in[14]; const float* b0b=(const float*)d_in[15];
  const float* W1 =(const float*)d_in[16]; const float* b1 =(const float*)d_in[17];
  const float* Wd1=(const float*)d_in[18]; const float* bd1=(const float*)d_in[19];
  const float* W2 =(const float*)d_in[20]; const float* b2 =(const float*)d_in[21];
  const float* Wd2=(const float*)d_in[22]; const float* bd2=(const float*)d_in[23];
  const float* W3 =(const float*)d_in[24]; const float* b3 =(const float*)d_in[25];
  const float* Wd3=(const float*)d_in[26]; const float* bd3=(const float*)d_in[27];
  float* out = (float*)d_out;
  float* ws = (float*)d_ws;

  size_t off = 0;
  auto alloc = [&](size_t nf){ size_t o = off; off += (nf + 63) & ~((size_t)63); return o; };
  size_t feats_o   = alloc((size_t)NPART*4);
  size_t bhfeats_o = alloc((size_t)NBHX*4);
  size_t rs_pp_o   = alloc(8256);
  size_t rs_bh_o   = alloc(8256);
  size_t gsrc_pp_o = alloc(EPX);
  size_t gbase_pp_o= alloc(EPX);
  size_t gw_pp_o   = alloc((size_t)EPX*8);
  size_t gsrc_bh_o = alloc(EBX);
  size_t gbase_bh_o= alloc(EBX);
  size_t gw_bh_o   = alloc((size_t)EBX*8);
  size_t h_o  = alloc((size_t)NPART*96);
  size_t h1_o = alloc((size_t)NPART*64);
  size_t h2_o = alloc((size_t)NPART*64);
  size_t T_o  = off;
  size_t ws_f = ws_size/4;
  size_t T_avail = (ws_f > T_o) ? (ws_f - T_o) : 0;

  float* featsP = ws + feats_o; float* bhfeatsP = ws + bhfeats_o;
  int* rsPP = (int*)(ws + rs_pp_o); int* rsBH = (int*)(ws + rs_bh_o);
  int* gsP = (int*)(ws + gsrc_pp_o); int* gbP = (int*)(ws + gbase_pp_o); float* gwP = ws + gw_pp_o;
  int* gsB = (int*)(ws + gsrc_bh_o); int* gbB = (int*)(ws + gbase_bh_o); float* gwB = ws + gw_bh_o;
  float* h  = ws + h_o; float* h1 = ws + h1_o; float* h2 = ws + h2_o;
  float* T  = ws + T_o;

  auto pick = [&](int KC)->int{
    int c = NPART;
    while (c > 32 && (size_t)c*KC > T_avail) c >>= 1;
    return c;
  };

  feats_kernel<<<(NPART+255)/256, 256, 0, stream>>>(vel, mass, bh_vel, bh_mass, featsP, bhfeatsP);
  geom_kernel<<<(EPX+255)/256, 256, 0, stream>>>(pos, pos, pp_src, pp_dst, EPX, NPART, 1.f/4.5f, gsP, gbP, gwP);
  geom_kernel<<<(EBX+255)/256, 256, 0, stream>>>(bh_pos, pos, bh_src, bh_dst, EBX, NPART, 1.f/18.f, gsB, gbB, gwB);
  csr_kernel<<<(NPART+1+255)/256, 256, 0, stream>>>(pp_dst, EPX, rsPP);
  csr_kernel<<<(NPART+1+255)/256, 256, 0, stream>>>(bh_dst, EBX, rsBH);

  // ---- layer 0: c0 (pp conv, CIN=4 -> 32), cb (bh conv, CIN=4 -> 32), d0 ----
  {
    int KC = 256, chunk = pick(KC);
    for (int m0 = 0; m0 < NPART; m0 += chunk) {
      scatter_kernel<4><<<chunk, 256, 0, stream>>>(rsPP, gsP, gbP, gwP, featsP, T, m0);
      gemm_kernel<32><<<chunk/32, 256, 0, stream>>>(T, KC, W0a, b0a, h, 96, 0, m0, 0);
    }
    for (int m0 = 0; m0 < NPART; m0 += chunk) {
      scatter_kernel<4><<<chunk, 256, 0, stream>>>(rsBH, gsB, gbB, gwB, bhfeatsP, T, m0);
      gemm_kernel<32><<<chunk/32, 256, 0, stream>>>(T, KC, W0b, b0b, h, 96, 32, m0, 0);
    }
    dense_kernel<4,32,0,0,0><<<((size_t)NPART*32+255)/256, 256, 0, stream>>>(featsP, Wd0, bd0, h, 96, 64, nullptr);
  }
  // ---- layer 1: h(96) -> h1 = relu(c1) + relu(d1), 64 ----
  {
    int KC = 6144, chunk = pick(KC);
    for (int m0 = 0; m0 < NPART; m0 += chunk) {
      scatter_kernel<96><<<chunk, 256, 0, stream>>>(rsPP, gsP, gbP, gwP, h, T, m0);
      gemm_kernel<64><<<chunk/32, 256, 0, stream>>>(T, KC, W1, b1, h1, 64, 0, m0, 1);
    }
    dense_kernel<96,64,1,1,0><<<((size_t)NPART*64+255)/256, 256, 0, stream>>>(h, Wd1, bd1, h1, 64, 0, nullptr);
  }
  // ---- layer 2: h1(64) -> h2 = relu(c2) + relu(d2) + h1 ----
  {
    int KC = 4096, chunk = pick(KC);
    for (int m0 = 0; m0 < NPART; m0 += chunk) {
      scatter_kernel<64><<<chunk, 256, 0, stream>>>(rsPP, gsP, gbP, gwP, h1, T, m0);
      gemm_kernel<64><<<chunk/32, 256, 0, stream>>>(T, KC, W2, b2, h2, 64, 0, m0, 1);
    }
    dense_kernel<64,64,1,1,1><<<((size_t)NPART*64+255)/256, 256, 0, stream>>>(h1, Wd2, bd2, h2, 64, 0, h1);
  }
  // ---- layer 3: h2(64) -> out = c3 + d3, 3 ----
  {
    int KC = 4096, chunk = pick(KC);
    for (int m0 = 0; m0 < NPART; m0 += chunk) {
      scatter_kernel<64><<<chunk, 256, 0, stream>>>(rsPP, gsP, gbP, gwP, h2, T, m0);
      int cn = (NPART - m0 < chunk) ? (NPART - m0) : chunk;
      conv3_kernel<<<((size_t)cn*3+255)/256, 256, 0, stream>>>(T, KC, W3, b3, out, m0, cn);
    }
    dense_kernel<64,3,0,1,0><<<((size_t)NPART*3+255)/256, 256, 0, stream>>>(h2, Wd3, bd3, out, 3, 0, nullptr);
  }
}

// Round 2
// 1146.777 us; speedup vs baseline: 3.2270x; 3.2270x over previous
//
#include <hip/hip_runtime.h>
#include <math.h>

#define NPART 8192
#define NBHX  64
#define EPX   300000
#define EBX   160000
#define FOUR_OVER_PI 1.27323954473516f

__device__ __forceinline__ float signf(float x){ return (x>0.f)?1.f:((x<0.f)?-1.f:0.f); }

// ---------------- feats build ----------------
__global__ void feats_kernel(const float* __restrict__ vel, const float* __restrict__ mass,
                             const float* __restrict__ bhvel, const float* __restrict__ bhmass,
                             float* __restrict__ feats, float* __restrict__ bhfeats) {
  int i = blockIdx.x*256 + threadIdx.x;
  if (i < NPART) {
    feats[i*4+0]=vel[i*3+0]; feats[i*4+1]=vel[i*3+1]; feats[i*4+2]=vel[i*3+2]; feats[i*4+3]=mass[i];
  }
  if (i < NBHX) {
    bhfeats[i*4+0]=bhvel[i*3+0]; bhfeats[i*4+1]=bhvel[i*3+1]; bhfeats[i*4+2]=bhvel[i*3+2]; bhfeats[i*4+3]=bhmass[i];
  }
}

// ---------------- edge geometry ----------------
__global__ void geom_kernel(const float* __restrict__ ppos, const float* __restrict__ qpos,
                            const int* __restrict__ src, const int* __restrict__ dst,
                            int E, int n_out, float inv_radius,
                            int* __restrict__ gsrc, int* __restrict__ gbase, float* __restrict__ gw) {
  int e = blockIdx.x*256 + threadIdx.x;
  if (e >= E) return;
  int s = src[e], t = dst[e];
  gsrc[e] = s;
  if (t >= n_out) { // padding edge, never referenced via CSR
    gbase[e] = 0;
    for (int j=0;j<8;j++) gw[(size_t)e*8+j] = 0.f;
    return;
  }
  float x = (ppos[s*3+0] - qpos[t*3+0]) * inv_radius;
  float y = (ppos[s*3+1] - qpos[t*3+1]) * inv_radius;
  float z = (ppos[s*3+2] - qpos[t*3+2]) * inv_radius;
  float r2 = x*x + y*y + z*z;
  float w1 = 1.f - r2;
  float win = fminf(fmaxf(w1*w1*w1, 0.f), 1.f);
  const float eps = 1e-8f;
  float sq = r2;
  float nrm = sqrtf(sq);
  float xy = x*x + y*y;
  bool caps = (1.25f*z*z > xy);
  float s_caps = sqrtf(3.f*nrm/(nrm + fabsf(z) + eps));
  float s_side = nrm / sqrtf(xy + eps);
  float sc = caps ? s_caps : s_side;
  bool valid = sq > eps;
  float cx = valid ? x*sc : 0.f;
  float cy = valid ? y*sc : 0.f;
  float cz = valid ? (caps ? signf(z)*nrm : 1.5f*z) : 0.f;
  float rxy = sqrtf(cx*cx + cy*cy);
  bool regA = (cx*cx >= cy*cy);
  float safe_cx = (fabsf(cx) > eps) ? cx : 1.0f;
  float safe_cy = (fabsf(cy) > eps) ? cy : 1.0f;
  float uA = signf(cx)*rxy;
  float vA = uA * FOUR_OVER_PI * atanf(cy/safe_cx);
  float vB = signf(cy)*rxy;
  float uB = vB * FOUR_OVER_PI * atanf(cx/safe_cy);
  bool okxy = rxy > eps;
  float u = okxy ? (regA ? uA : uB) : 0.f;
  float v = okxy ? (regA ? vA : vB) : 0.f;
  float tt[3] = { (u+1.f)*1.5f, (v+1.f)*1.5f, (cz+1.f)*1.5f };
  int i0[3]; float f[3];
#pragma unroll
  for (int ax=0; ax<3; ax++) {
    float tf = floorf(tt[ax]);
    tf = fminf(fmaxf(tf, 0.f), 2.f);
    i0[ax] = (int)tf;
    f[ax] = tt[ax] - tf;
  }
  gbase[e] = (i0[0]*4 + i0[1])*4 + i0[2];
#pragma unroll
  for (int j=0;j<8;j++) {
    float wx = (j&4) ? f[0] : 1.f - f[0];
    float wy = (j&2) ? f[1] : 1.f - f[1];
    float wz = (j&1) ? f[2] : 1.f - f[2];
    gw[(size_t)e*8+j] = win * wx * wy * wz;
  }
}

// ---------------- CSR row offsets (dst sorted non-decreasing) ----------------
__global__ void csr_kernel(const int* __restrict__ dst, int E, int* __restrict__ rs) {
  int n = blockIdx.x*256 + threadIdx.x;
  if (n > NPART) return;
  int lo = 0, hi = E;
  while (lo < hi) { int mid = (lo+hi)>>1; if (dst[mid] < n) lo = mid+1; else hi = mid; }
  rs[n] = lo;
}

// ---------------- scatter v2: one wave per node, LDS RMW, NO atomics ----------------
// Within a wave, lanes are lockstep and DS ops complete in order -> plain +=
// is race-free as long as no two lanes in one instruction hit the same slot.
// For a fixed edge the 8 corner indices are distinct, and lane==channel, so
// all touched slots are distinct. All 8 reads are issued before all 8 writes
// so the DS pipe can pipeline instead of serializing RMW pairs.
template<int CIN>
__global__ __launch_bounds__(128) void scatter2_kernel(
    const int* __restrict__ rs, const int* __restrict__ gsrc, const int* __restrict__ gbase,
    const float* __restrict__ gw, const float* __restrict__ feats,
    float* __restrict__ T, int m0) {
  constexpr int ROW = 64*CIN;
  __shared__ __align__(16) float Tl[2*ROW];
  const int lane = threadIdx.x & 63;
  const int wid  = threadIdx.x >> 6;
  float* Tw = Tl + wid*ROW;
  const int nodeL = blockIdx.x*2 + wid;
  float4 z4; z4.x=0.f; z4.y=0.f; z4.z=0.f; z4.w=0.f;
  for (int i = lane; i < ROW/4; i += 64) ((float4*)Tw)[i] = z4;
  const int e0 = rs[m0 + nodeL], e1 = rs[m0 + nodeL + 1];
  if constexpr (CIN == 4) {
    const int j = (lane >> 2) & 7;
    const int c = lane & 3;
    const int koff = ((j&4)<<2) | ((j&2)<<1) | (j&1);
    for (int e = e0; e < e1; e++) {
      int s    = gsrc[e];
      int base = gbase[e];
      float w  = gw[(size_t)e*8 + j];
      float F  = feats[s*4 + c];
      if (lane < 32) {
        int a = (base + koff)*4 + c;
        Tw[a] += w * F;
      }
    }
  } else {
    for (int e = e0; e < e1; e++) {
      int s    = gsrc[e];
      int base = gbase[e];
      float4 wA = *(const float4*)(gw + (size_t)e*8);
      float4 wB = *(const float4*)(gw + (size_t)e*8 + 4);
      float F0 = feats[(size_t)s*CIN + lane];
      float F1 = 0.f;
      if constexpr (CIN == 96) { if (lane < 32) F1 = feats[(size_t)s*CIN + 64 + lane]; }
      float wj0=wA.x, wj1=wA.y, wj2=wA.z, wj3=wA.w, wj4=wB.x, wj5=wB.y, wj6=wB.z, wj7=wB.w;
      int a[8]; float r[8];
#pragma unroll
      for (int j=0;j<8;j++) {
        int koff = ((j&4)<<2) | ((j&2)<<1) | (j&1);
        a[j] = (base + koff)*CIN + lane;
        r[j] = Tw[a[j]];
      }
      Tw[a[0]] = r[0] + wj0*F0;
      Tw[a[1]] = r[1] + wj1*F0;
      Tw[a[2]] = r[2] + wj2*F0;
      Tw[a[3]] = r[3] + wj3*F0;
      Tw[a[4]] = r[4] + wj4*F0;
      Tw[a[5]] = r[5] + wj5*F0;
      Tw[a[6]] = r[6] + wj6*F0;
      Tw[a[7]] = r[7] + wj7*F0;
      if constexpr (CIN == 96) {
        if (lane < 32) {
          float r2v[8];
#pragma unroll
          for (int j=0;j<8;j++) r2v[j] = Tw[a[j] + 64];
          Tw[a[0]+64] = r2v[0] + wj0*F1;
          Tw[a[1]+64] = r2v[1] + wj1*F1;
          Tw[a[2]+64] = r2v[2] + wj2*F1;
          Tw[a[3]+64] = r2v[3] + wj3*F1;
          Tw[a[4]+64] = r2v[4] + wj4*F1;
          Tw[a[5]+64] = r2v[5] + wj5*F1;
          Tw[a[6]+64] = r2v[6] + wj6*F1;
          Tw[a[7]+64] = r2v[7] + wj7*F1;
        }
      }
    }
  }
  float* To = T + (size_t)nodeL*ROW;
  for (int i = lane; i < ROW/4; i += 64) ((float4*)To)[i] = ((const float4*)Tw)[i];
}

// ---------------- tiled f32 GEMM (unchanged, known-correct) ----------------
template<int COUT>
__global__ __launch_bounds__(256) void gemm_kernel(
    const float* __restrict__ T, int KC, const float* __restrict__ W,
    const float* __restrict__ b, float* __restrict__ out,
    int ldo, int coff, int m0, int relu) {
  constexpr int BM = 32, BK = 32;
  constexpr int NG = 256 / COUT;
  constexpr int RPT = BM / NG;
  __shared__ float Tt[BM*BK];
  __shared__ float Wt[BK*COUT];
  int d = threadIdx.x % COUT;
  int rg = threadIdx.x / COUT;
  float acc[RPT];
#pragma unroll
  for (int i=0;i<RPT;i++) acc[i] = 0.f;
  const float* Trow = T + (size_t)blockIdx.x*BM*KC;
  for (int k0 = 0; k0 < KC; k0 += BK) {
    {
      int idx = threadIdx.x*4;
      int r = idx / BK, cc = idx % BK;
      *(float4*)(Tt + idx) = *(const float4*)(Trow + (size_t)r*KC + k0 + cc);
    }
    for (int i = threadIdx.x*4; i < BK*COUT; i += 1024) {
      int r = i / COUT, cc = i % COUT;
      *(float4*)(Wt + i) = *(const float4*)(W + (size_t)(k0+r)*COUT + cc);
    }
    __syncthreads();
#pragma unroll 8
    for (int k2 = 0; k2 < BK; k2++) {
      float wv = Wt[k2*COUT + d];
#pragma unroll
      for (int i=0;i<RPT;i++) acc[i] += Tt[(rg + NG*i)*BK + k2] * wv;
    }
    __syncthreads();
  }
  float bb = b[d];
#pragma unroll
  for (int i=0;i<RPT;i++) {
    float v = acc[i] + bb;
    if (relu) v = fmaxf(v, 0.f);
    int row = m0 + blockIdx.x*BM + rg + NG*i;
    out[(size_t)row*ldo + coff + d] = v;
  }
}

// ---------------- final conv layer, COUT=3: block-per-node k-split reduction ----------------
__global__ __launch_bounds__(256) void conv3b_kernel(
    const float* __restrict__ T, int KC, const float* __restrict__ W,
    const float* __restrict__ b, float* __restrict__ out, int m0, int cn) {
  int n = blockIdx.x;
  if (n >= cn) return;
  const float* Trow = T + (size_t)n*KC;
  float a0=0.f, a1=0.f, a2=0.f;
  for (int k = threadIdx.x; k < KC; k += 256) {
    float t = Trow[k];
    a0 += t*W[k*3+0]; a1 += t*W[k*3+1]; a2 += t*W[k*3+2];
  }
#pragma unroll
  for (int off=32; off>=1; off>>=1) {
    a0 += __shfl_down(a0, off);
    a1 += __shfl_down(a1, off);
    a2 += __shfl_down(a2, off);
  }
  __shared__ float red[4][3];
  int wv = threadIdx.x >> 6;
  if ((threadIdx.x & 63) == 0) { red[wv][0]=a0; red[wv][1]=a1; red[wv][2]=a2; }
  __syncthreads();
  if (threadIdx.x == 0) {
    float s0 = red[0][0]+red[1][0]+red[2][0]+red[3][0] + b[0];
    float s1 = red[0][1]+red[1][1]+red[2][1]+red[3][1] + b[1];
    float s2 = red[0][2]+red[1][2]+red[2][2]+red[3][2] + b[2];
    size_t o = (size_t)(m0+n)*3;
    out[o+0]=s0; out[o+1]=s1; out[o+2]=s2;
  }
}

// ---------------- dense (1x1) layers ----------------
template<int CIN, int COUT, int RELU, int ACCUM, int ADDSKIP>
__global__ void dense_kernel(const float* __restrict__ X, const float* __restrict__ Wd,
                             const float* __restrict__ bd, float* __restrict__ out,
                             int ldo, int coff, const float* __restrict__ skip) {
  int idx = blockIdx.x*256 + threadIdx.x;
  if (idx >= NPART*COUT) return;
  int n = idx / COUT, d = idx - n*COUT;
  float acc = bd[d];
  const float* x = X + (size_t)n*CIN;
#pragma unroll 4
  for (int c=0;c<CIN;c++) acc += x[c]*Wd[c*COUT + d];
  if (RELU) acc = fmaxf(acc, 0.f);
  if (ADDSKIP) acc += skip[(size_t)n*COUT + d];
  float* o = out + (size_t)n*ldo + coff + d;
  if (ACCUM) *o += acc; else *o = acc;
}

extern "C" void kernel_launch(void* const* d_in, const int* in_sizes, int n_in,
                              void* d_out, int out_size, void* d_ws, size_t ws_size,
                              hipStream_t stream) {
  const float* pos    = (const float*)d_in[0];
  const float* vel    = (const float*)d_in[1];
  const float* mass   = (const float*)d_in[2];
  const float* bh_pos = (const float*)d_in[3];
  const float* bh_vel = (const float*)d_in[4];
  const float* bh_mass= (const float*)d_in[5];
  const int* pp_src   = (const int*)d_in[6];
  const int* pp_dst   = (const int*)d_in[7];
  const int* bh_src   = (const int*)d_in[8];
  const int* bh_dst   = (const int*)d_in[9];
  const float* W0a=(const float*)d_in[10]; const float* b0a=(const float*)d_in[11];
  const float* Wd0=(const float*)d_in[12]; const float* bd0=(const float*)d_in[13];
  const float* W0b=(const float*)d_in[14]; const float* b0b=(const float*)d_in[15];
  const float* W1 =(const float*)d_in[16]; const float* b1 =(const float*)d_in[17];
  const float* Wd1=(const float*)d_in[18]; const float* bd1=(const float*)d_in[19];
  const float* W2 =(const float*)d_in[20]; const float* b2 =(const float*)d_in[21];
  const float* Wd2=(const float*)d_in[22]; const float* bd2=(const float*)d_in[23];
  const float* W3 =(const float*)d_in[24]; const float* b3 =(const float*)d_in[25];
  const float* Wd3=(const float*)d_in[26]; const float* bd3=(const float*)d_in[27];
  float* out = (float*)d_out;
  float* ws = (float*)d_ws;

  size_t off = 0;
  auto alloc = [&](size_t nf){ size_t o = off; off += (nf + 63) & ~((size_t)63); return o; };
  size_t feats_o   = alloc((size_t)NPART*4);
  size_t bhfeats_o = alloc((size_t)NBHX*4);
  size_t rs_pp_o   = alloc(8256);
  size_t rs_bh_o   = alloc(8256);
  size_t gsrc_pp_o = alloc(EPX);
  size_t gbase_pp_o= alloc(EPX);
  size_t gw_pp_o   = alloc((size_t)EPX*8);
  size_t gsrc_bh_o = alloc(EBX);
  size_t gbase_bh_o= alloc(EBX);
  size_t gw_bh_o   = alloc((size_t)EBX*8);
  size_t h_o  = alloc((size_t)NPART*96);
  size_t h1_o = alloc((size_t)NPART*64);
  size_t h2_o = alloc((size_t)NPART*64);
  size_t T_o  = off;
  size_t ws_f = ws_size/4;
  size_t T_avail = (ws_f > T_o) ? (ws_f - T_o) : 0;

  float* featsP = ws + feats_o; float* bhfeatsP = ws + bhfeats_o;
  int* rsPP = (int*)(ws + rs_pp_o); int* rsBH = (int*)(ws + rs_bh_o);
  int* gsP = (int*)(ws + gsrc_pp_o); int* gbP = (int*)(ws + gbase_pp_o); float* gwP = ws + gw_pp_o;
  int* gsB = (int*)(ws + gsrc_bh_o); int* gbB = (int*)(ws + gbase_bh_o); float* gwB = ws + gw_bh_o;
  float* h  = ws + h_o; float* h1 = ws + h1_o; float* h2 = ws + h2_o;
  float* T  = ws + T_o;

  auto pick = [&](int KC)->int{
    int c = NPART;
    while (c > 32 && (size_t)c*KC > T_avail) c >>= 1;
    return c;
  };

  feats_kernel<<<(NPART+255)/256, 256, 0, stream>>>(vel, mass, bh_vel, bh_mass, featsP, bhfeatsP);
  geom_kernel<<<(EPX+255)/256, 256, 0, stream>>>(pos, pos, pp_src, pp_dst, EPX, NPART, 1.f/4.5f, gsP, gbP, gwP);
  geom_kernel<<<(EBX+255)/256, 256, 0, stream>>>(bh_pos, pos, bh_src, bh_dst, EBX, NPART, 1.f/18.f, gsB, gbB, gwB);
  csr_kernel<<<(NPART+1+255)/256, 256, 0, stream>>>(pp_dst, EPX, rsPP);
  csr_kernel<<<(NPART+1+255)/256, 256, 0, stream>>>(bh_dst, EBX, rsBH);

  // ---- layer 0: c0 (pp conv, 4->32), cb (bh conv, 4->32), d0 ----
  {
    int KC = 256, chunk = pick(KC);
    for (int m0 = 0; m0 < NPART; m0 += chunk) {
      scatter2_kernel<4><<<chunk/2, 128, 0, stream>>>(rsPP, gsP, gbP, gwP, featsP, T, m0);
      gemm_kernel<32><<<chunk/32, 256, 0, stream>>>(T, KC, W0a, b0a, h, 96, 0, m0, 0);
    }
    for (int m0 = 0; m0 < NPART; m0 += chunk) {
      scatter2_kernel<4><<<chunk/2, 128, 0, stream>>>(rsBH, gsB, gbB, gwB, bhfeatsP, T, m0);
      gemm_kernel<32><<<chunk/32, 256, 0, stream>>>(T, KC, W0b, b0b, h, 96, 32, m0, 0);
    }
    dense_kernel<4,32,0,0,0><<<((size_t)NPART*32+255)/256, 256, 0, stream>>>(featsP, Wd0, bd0, h, 96, 64, nullptr);
  }
  // ---- layer 1: h(96) -> h1 = relu(c1) + relu(d1), 64 ----
  {
    int KC = 6144, chunk = pick(KC);
    for (int m0 = 0; m0 < NPART; m0 += chunk) {
      scatter2_kernel<96><<<chunk/2, 128, 0, stream>>>(rsPP, gsP, gbP, gwP, h, T, m0);
      gemm_kernel<64><<<chunk/32, 256, 0, stream>>>(T, KC, W1, b1, h1, 64, 0, m0, 1);
    }
    dense_kernel<96,64,1,1,0><<<((size_t)NPART*64+255)/256, 256, 0, stream>>>(h, Wd1, bd1, h1, 64, 0, nullptr);
  }
  // ---- layer 2: h1(64) -> h2 = relu(c2) + relu(d2) + h1 ----
  {
    int KC = 4096, chunk = pick(KC);
    for (int m0 = 0; m0 < NPART; m0 += chunk) {
      scatter2_kernel<64><<<chunk/2, 128, 0, stream>>>(rsPP, gsP, gbP, gwP, h1, T, m0);
      gemm_kernel<64><<<chunk/32, 256, 0, stream>>>(T, KC, W2, b2, h2, 64, 0, m0, 1);
    }
    dense_kernel<64,64,1,1,1><<<((size_t)NPART*64+255)/256, 256, 0, stream>>>(h1, Wd2, bd2, h2, 64, 0, h1);
  }
  // ---- layer 3: h2(64) -> out = c3 + d3, 3 ----
  {
    int KC = 4096, chunk = pick(KC);
    for (int m0 = 0; m0 < NPART; m0 += chunk) {
      scatter2_kernel<64><<<chunk/2, 128, 0, stream>>>(rsPP, gsP, gbP, gwP, h2, T, m0);
      int cn = (NPART - m0 < chunk) ? (NPART - m0) : chunk;
      conv3b_kernel<<<cn, 256, 0, stream>>>(T, KC, W3, b3, out, m0, cn);
    }
    dense_kernel<64,3,0,1,0><<<((size_t)NPART*3+255)/256, 256, 0, stream>>>(h2, Wd3, bd3, out, 3, 0, nullptr);
  }
}

// Round 3
// 620.157 us; speedup vs baseline: 5.9674x; 1.8492x over previous
//
#include <hip/hip_runtime.h>
#include <math.h>

#define NPART 8192
#define NBHX  64
#define EPX   300000
#define EBX   160000
#define KSPLIT 8
#define FOUR_OVER_PI 1.27323954473516f

__device__ __forceinline__ float signf(float x){ return (x>0.f)?1.f:((x<0.f)?-1.f:0.f); }

// ---------------- feats build ----------------
__global__ void feats_kernel(const float* __restrict__ vel, const float* __restrict__ mass,
                             const float* __restrict__ bhvel, const float* __restrict__ bhmass,
                             float* __restrict__ feats, float* __restrict__ bhfeats) {
  int i = blockIdx.x*256 + threadIdx.x;
  if (i < NPART) {
    feats[i*4+0]=vel[i*3+0]; feats[i*4+1]=vel[i*3+1]; feats[i*4+2]=vel[i*3+2]; feats[i*4+3]=mass[i];
  }
  if (i < NBHX) {
    bhfeats[i*4+0]=bhvel[i*3+0]; bhfeats[i*4+1]=bhvel[i*3+1]; bhfeats[i*4+2]=bhvel[i*3+2]; bhfeats[i*4+3]=bhmass[i];
  }
}

// ---------------- edge geometry ----------------
__global__ void geom_kernel(const float* __restrict__ ppos, const float* __restrict__ qpos,
                            const int* __restrict__ src, const int* __restrict__ dst,
                            int E, int n_out, float inv_radius,
                            int* __restrict__ gsrc, int* __restrict__ gbase, float* __restrict__ gw) {
  int e = blockIdx.x*256 + threadIdx.x;
  if (e >= E) return;
  int s = src[e], t = dst[e];
  gsrc[e] = s;
  if (t >= n_out) { // padding edge, never referenced via CSR
    gbase[e] = 0;
    for (int j=0;j<8;j++) gw[(size_t)e*8+j] = 0.f;
    return;
  }
  float x = (ppos[s*3+0] - qpos[t*3+0]) * inv_radius;
  float y = (ppos[s*3+1] - qpos[t*3+1]) * inv_radius;
  float z = (ppos[s*3+2] - qpos[t*3+2]) * inv_radius;
  float r2 = x*x + y*y + z*z;
  float w1 = 1.f - r2;
  float win = fminf(fmaxf(w1*w1*w1, 0.f), 1.f);
  const float eps = 1e-8f;
  float sq = r2;
  float nrm = sqrtf(sq);
  float xy = x*x + y*y;
  bool caps = (1.25f*z*z > xy);
  float s_caps = sqrtf(3.f*nrm/(nrm + fabsf(z) + eps));
  float s_side = nrm / sqrtf(xy + eps);
  float sc = caps ? s_caps : s_side;
  bool valid = sq > eps;
  float cx = valid ? x*sc : 0.f;
  float cy = valid ? y*sc : 0.f;
  float cz = valid ? (caps ? signf(z)*nrm : 1.5f*z) : 0.f;
  float rxy = sqrtf(cx*cx + cy*cy);
  bool regA = (cx*cx >= cy*cy);
  float safe_cx = (fabsf(cx) > eps) ? cx : 1.0f;
  float safe_cy = (fabsf(cy) > eps) ? cy : 1.0f;
  float uA = signf(cx)*rxy;
  float vA = uA * FOUR_OVER_PI * atanf(cy/safe_cx);
  float vB = signf(cy)*rxy;
  float uB = vB * FOUR_OVER_PI * atanf(cx/safe_cy);
  bool okxy = rxy > eps;
  float u = okxy ? (regA ? uA : uB) : 0.f;
  float v = okxy ? (regA ? vA : vB) : 0.f;
  float tt[3] = { (u+1.f)*1.5f, (v+1.f)*1.5f, (cz+1.f)*1.5f };
  int i0[3]; float f[3];
#pragma unroll
  for (int ax=0; ax<3; ax++) {
    float tf = floorf(tt[ax]);
    tf = fminf(fmaxf(tf, 0.f), 2.f);
    i0[ax] = (int)tf;
    f[ax] = tt[ax] - tf;
  }
  gbase[e] = (i0[0]*4 + i0[1])*4 + i0[2];
#pragma unroll
  for (int j=0;j<8;j++) {
    float wx = (j&4) ? f[0] : 1.f - f[0];
    float wy = (j&2) ? f[1] : 1.f - f[1];
    float wz = (j&1) ? f[2] : 1.f - f[2];
    gw[(size_t)e*8+j] = win * wx * wy * wz;
  }
}

// ---------------- CSR row offsets (dst sorted non-decreasing) ----------------
__global__ void csr_kernel(const int* __restrict__ dst, int E, int* __restrict__ rs) {
  int n = blockIdx.x*256 + threadIdx.x;
  if (n > NPART) return;
  int lo = 0, hi = E;
  while (lo < hi) { int mid = (lo+hi)>>1; if (dst[mid] < n) lo = mid+1; else hi = mid; }
  rs[n] = lo;
}

// ---------------- scatter: one wave per node, LDS RMW, NO atomics ----------------
template<int CIN>
__global__ __launch_bounds__(128) void scatter2_kernel(
    const int* __restrict__ rs, const int* __restrict__ gsrc, const int* __restrict__ gbase,
    const float* __restrict__ gw, const float* __restrict__ feats,
    float* __restrict__ T, int m0) {
  constexpr int ROW = 64*CIN;
  __shared__ __align__(16) float Tl[2*ROW];
  const int lane = threadIdx.x & 63;
  const int wid  = threadIdx.x >> 6;
  float* Tw = Tl + wid*ROW;
  const int nodeL = blockIdx.x*2 + wid;
  float4 z4; z4.x=0.f; z4.y=0.f; z4.z=0.f; z4.w=0.f;
  for (int i = lane; i < ROW/4; i += 64) ((float4*)Tw)[i] = z4;
  const int e0 = rs[m0 + nodeL], e1 = rs[m0 + nodeL + 1];
  if constexpr (CIN == 4) {
    const int j = (lane >> 2) & 7;
    const int c = lane & 3;
    const int koff = ((j&4)<<2) | ((j&2)<<1) | (j&1);
    for (int e = e0; e < e1; e++) {
      int s    = gsrc[e];
      int base = gbase[e];
      float w  = gw[(size_t)e*8 + j];
      float F  = feats[s*4 + c];
      if (lane < 32) {
        int a = (base + koff)*4 + c;
        Tw[a] += w * F;
      }
    }
  } else {
    for (int e = e0; e < e1; e++) {
      int s    = gsrc[e];
      int base = gbase[e];
      float4 wA = *(const float4*)(gw + (size_t)e*8);
      float4 wB = *(const float4*)(gw + (size_t)e*8 + 4);
      float F0 = feats[(size_t)s*CIN + lane];
      float F1 = 0.f;
      if constexpr (CIN == 96) { if (lane < 32) F1 = feats[(size_t)s*CIN + 64 + lane]; }
      float wj0=wA.x, wj1=wA.y, wj2=wA.z, wj3=wA.w, wj4=wB.x, wj5=wB.y, wj6=wB.z, wj7=wB.w;
      int a[8]; float r[8];
#pragma unroll
      for (int j=0;j<8;j++) {
        int koff = ((j&4)<<2) | ((j&2)<<1) | (j&1);
        a[j] = (base + koff)*CIN + lane;
        r[j] = Tw[a[j]];
      }
      Tw[a[0]] = r[0] + wj0*F0;
      Tw[a[1]] = r[1] + wj1*F0;
      Tw[a[2]] = r[2] + wj2*F0;
      Tw[a[3]] = r[3] + wj3*F0;
      Tw[a[4]] = r[4] + wj4*F0;
      Tw[a[5]] = r[5] + wj5*F0;
      Tw[a[6]] = r[6] + wj6*F0;
      Tw[a[7]] = r[7] + wj7*F0;
      if constexpr (CIN == 96) {
        if (lane < 32) {
          float r2v[8];
#pragma unroll
          for (int j=0;j<8;j++) r2v[j] = Tw[a[j] + 64];
          Tw[a[0]+64] = r2v[0] + wj0*F1;
          Tw[a[1]+64] = r2v[1] + wj1*F1;
          Tw[a[2]+64] = r2v[2] + wj2*F1;
          Tw[a[3]+64] = r2v[3] + wj3*F1;
          Tw[a[4]+64] = r2v[4] + wj4*F1;
          Tw[a[5]+64] = r2v[5] + wj5*F1;
          Tw[a[6]+64] = r2v[6] + wj6*F1;
          Tw[a[7]+64] = r2v[7] + wj7*F1;
        }
      }
    }
  }
  float* To = T + (size_t)nodeL*ROW;
  for (int i = lane; i < ROW/4; i += 64) ((float4*)To)[i] = ((const float4*)Tw)[i];
}

// ---------------- register-tiled f32 GEMM, COUT=64, K-split ----------------
// grid: (M/128, KSPLIT). 256 thr. 8x4 micro-tile -> 32 FMA per 9 LDS reads.
__global__ __launch_bounds__(256) void gemm64_kernel(
    const float* __restrict__ T, int KC, const float* __restrict__ W,
    float* __restrict__ P, int chunk) {
  __shared__ float Tt[128][33];
  __shared__ float Wt[32][64];
  const int s = blockIdx.y;
  const int kc_per = KC / KSPLIT;
  const int k_begin = s * kc_per;
  const int tid = threadIdx.x;
  const int tx = tid & 15, ty = tid >> 4;
  const int m_base = blockIdx.x * 128;
  float acc[8][4];
#pragma unroll
  for (int i=0;i<8;i++)
#pragma unroll
    for (int c=0;c<4;c++) acc[i][c] = 0.f;
  const float* Tb = T + (size_t)m_base*KC;
  const int ml = tid >> 3, kq = (tid & 7) << 2;
  for (int k0 = k_begin; k0 < k_begin + kc_per; k0 += 32) {
#pragma unroll
    for (int j = 0; j < 4; j++) {
      float4 v = *(const float4*)(Tb + (size_t)(ml + 32*j)*KC + k0 + kq);
      Tt[ml+32*j][kq+0] = v.x; Tt[ml+32*j][kq+1] = v.y;
      Tt[ml+32*j][kq+2] = v.z; Tt[ml+32*j][kq+3] = v.w;
    }
#pragma unroll
    for (int j = 0; j < 2; j++) {
      int idx = tid*2 + j;
      int r = idx >> 4, c4 = (idx & 15) << 2;
      *(float4*)(&Wt[r][c4]) = *(const float4*)(W + (size_t)(k0+r)*64 + c4);
    }
    __syncthreads();
#pragma unroll 4
    for (int k2 = 0; k2 < 32; k2++) {
      float wv0 = Wt[k2][tx*4+0], wv1 = Wt[k2][tx*4+1], wv2 = Wt[k2][tx*4+2], wv3 = Wt[k2][tx*4+3];
      float tv[8];
#pragma unroll
      for (int i=0;i<8;i++) tv[i] = Tt[ty*8+i][k2];
#pragma unroll
      for (int i=0;i<8;i++) {
        acc[i][0] += tv[i]*wv0; acc[i][1] += tv[i]*wv1;
        acc[i][2] += tv[i]*wv2; acc[i][3] += tv[i]*wv3;
      }
    }
    __syncthreads();
  }
  float* Pp = P + ((size_t)s*chunk + m_base)*64;
#pragma unroll
  for (int i=0;i<8;i++) {
    int m = ty*8+i;
    *(float4*)(Pp + (size_t)m*64 + tx*4) = *(const float4*)(acc[i]);
  }
}

__global__ void reduce64_kernel(const float* __restrict__ P, int chunk,
    const float* __restrict__ b, float* __restrict__ out, int ldo, int coff, int m0, int relu) {
  int idx = blockIdx.x*256 + threadIdx.x;
  if (idx >= chunk*64) return;
  int m = idx >> 6, d = idx & 63;
  float a = b[d];
#pragma unroll
  for (int s=0;s<KSPLIT;s++) a += P[((size_t)s*chunk + m)*64 + d];
  if (relu) a = fmaxf(a, 0.f);
  out[(size_t)(m0+m)*ldo + coff + d] = a;
}

// ---------------- old tiled f32 GEMM (kept for COUT=32 layer-0 and fallback) ----------------
template<int COUT>
__global__ __launch_bounds__(256) void gemm_kernel(
    const float* __restrict__ T, int KC, const float* __restrict__ W,
    const float* __restrict__ b, float* __restrict__ out,
    int ldo, int coff, int m0, int relu) {
  constexpr int BM = 32, BK = 32;
  constexpr int NG = 256 / COUT;
  constexpr int RPT = BM / NG;
  __shared__ float Tt[BM*BK];
  __shared__ float Wt[BK*COUT];
  int d = threadIdx.x % COUT;
  int rg = threadIdx.x / COUT;
  float acc[RPT];
#pragma unroll
  for (int i=0;i<RPT;i++) acc[i] = 0.f;
  const float* Trow = T + (size_t)blockIdx.x*BM*KC;
  for (int k0 = 0; k0 < KC; k0 += BK) {
    {
      int idx = threadIdx.x*4;
      int r = idx / BK, cc = idx % BK;
      *(float4*)(Tt + idx) = *(const float4*)(Trow + (size_t)r*KC + k0 + cc);
    }
    for (int i = threadIdx.x*4; i < BK*COUT; i += 1024) {
      int r = i / COUT, cc = i % COUT;
      *(float4*)(Wt + i) = *(const float4*)(W + (size_t)(k0+r)*COUT + cc);
    }
    __syncthreads();
#pragma unroll 8
    for (int k2 = 0; k2 < BK; k2++) {
      float wv = Wt[k2*COUT + d];
#pragma unroll
      for (int i=0;i<RPT;i++) acc[i] += Tt[(rg + NG*i)*BK + k2] * wv;
    }
    __syncthreads();
  }
  float bb = b[d];
#pragma unroll
  for (int i=0;i<RPT;i++) {
    float v = acc[i] + bb;
    if (relu) v = fmaxf(v, 0.f);
    int row = m0 + blockIdx.x*BM + rg + NG*i;
    out[(size_t)row*ldo + coff + d] = v;
  }
}

// ---------------- final conv layer, COUT=3: block-per-node k-split reduction ----------------
__global__ __launch_bounds__(256) void conv3b_kernel(
    const float* __restrict__ T, int KC, const float* __restrict__ W,
    const float* __restrict__ b, float* __restrict__ out, int m0, int cn) {
  int n = blockIdx.x;
  if (n >= cn) return;
  const float* Trow = T + (size_t)n*KC;
  float a0=0.f, a1=0.f, a2=0.f;
  for (int k = threadIdx.x; k < KC; k += 256) {
    float t = Trow[k];
    a0 += t*W[k*3+0]; a1 += t*W[k*3+1]; a2 += t*W[k*3+2];
  }
#pragma unroll
  for (int off=32; off>=1; off>>=1) {
    a0 += __shfl_down(a0, off);
    a1 += __shfl_down(a1, off);
    a2 += __shfl_down(a2, off);
  }
  __shared__ float red[4][3];
  int wv = threadIdx.x >> 6;
  if ((threadIdx.x & 63) == 0) { red[wv][0]=a0; red[wv][1]=a1; red[wv][2]=a2; }
  __syncthreads();
  if (threadIdx.x == 0) {
    float s0 = red[0][0]+red[1][0]+red[2][0]+red[3][0] + b[0];
    float s1 = red[0][1]+red[1][1]+red[2][1]+red[3][1] + b[1];
    float s2 = red[0][2]+red[1][2]+red[2][2]+red[3][2] + b[2];
    size_t o = (size_t)(m0+n)*3;
    out[o+0]=s0; out[o+1]=s1; out[o+2]=s2;
  }
}

// ---------------- dense (1x1) layers ----------------
template<int CIN, int COUT, int RELU, int ACCUM, int ADDSKIP>
__global__ void dense_kernel(const float* __restrict__ X, const float* __restrict__ Wd,
                             const float* __restrict__ bd, float* __restrict__ out,
                             int ldo, int coff, const float* __restrict__ skip) {
  int idx = blockIdx.x*256 + threadIdx.x;
  if (idx >= NPART*COUT) return;
  int n = idx / COUT, d = idx - n*COUT;
  float acc = bd[d];
  const float* x = X + (size_t)n*CIN;
#pragma unroll 4
  for (int c=0;c<CIN;c++) acc += x[c]*Wd[c*COUT + d];
  if (RELU) acc = fmaxf(acc, 0.f);
  if (ADDSKIP) acc += skip[(size_t)n*COUT + d];
  float* o = out + (size_t)n*ldo + coff + d;
  if (ACCUM) *o += acc; else *o = acc;
}

extern "C" void kernel_launch(void* const* d_in, const int* in_sizes, int n_in,
                              void* d_out, int out_size, void* d_ws, size_t ws_size,
                              hipStream_t stream) {
  const float* pos    = (const float*)d_in[0];
  const float* vel    = (const float*)d_in[1];
  const float* mass   = (const float*)d_in[2];
  const float* bh_pos = (const float*)d_in[3];
  const float* bh_vel = (const float*)d_in[4];
  const float* bh_mass= (const float*)d_in[5];
  const int* pp_src   = (const int*)d_in[6];
  const int* pp_dst   = (const int*)d_in[7];
  const int* bh_src   = (const int*)d_in[8];
  const int* bh_dst   = (const int*)d_in[9];
  const float* W0a=(const float*)d_in[10]; const float* b0a=(const float*)d_in[11];
  const float* Wd0=(const float*)d_in[12]; const float* bd0=(const float*)d_in[13];
  const float* W0b=(const float*)d_in[14]; const float* b0b=(const float*)d_in[15];
  const float* W1 =(const float*)d_in[16]; const float* b1 =(const float*)d_in[17];
  const float* Wd1=(const float*)d_in[18]; const float* bd1=(const float*)d_in[19];
  const float* W2 =(const float*)d_in[20]; const float* b2 =(const float*)d_in[21];
  const float* Wd2=(const float*)d_in[22]; const float* bd2=(const float*)d_in[23];
  const float* W3 =(const float*)d_in[24]; const float* b3 =(const float*)d_in[25];
  const float* Wd3=(const float*)d_in[26]; const float* bd3=(const float*)d_in[27];
  float* out = (float*)d_out;
  float* ws = (float*)d_ws;

  size_t off = 0;
  auto alloc = [&](size_t nf){ size_t o = off; off += (nf + 63) & ~((size_t)63); return o; };
  size_t feats_o   = alloc((size_t)NPART*4);
  size_t bhfeats_o = alloc((size_t)NBHX*4);
  size_t rs_pp_o   = alloc(8256);
  size_t rs_bh_o   = alloc(8256);
  size_t gsrc_pp_o = alloc(EPX);
  size_t gbase_pp_o= alloc(EPX);
  size_t gw_pp_o   = alloc((size_t)EPX*8);
  size_t gsrc_bh_o = alloc(EBX);
  size_t gbase_bh_o= alloc(EBX);
  size_t gw_bh_o   = alloc((size_t)EBX*8);
  size_t h_o  = alloc((size_t)NPART*96);
  size_t h1_o = alloc((size_t)NPART*64);
  size_t h2_o = alloc((size_t)NPART*64);
  size_t P_o  = alloc((size_t)KSPLIT*NPART*64);
  size_t T_o  = off;
  size_t ws_f = ws_size/4;
  size_t T_avail = (ws_f > T_o) ? (ws_f - T_o) : 0;

  float* featsP = ws + feats_o; float* bhfeatsP = ws + bhfeats_o;
  int* rsPP = (int*)(ws + rs_pp_o); int* rsBH = (int*)(ws + rs_bh_o);
  int* gsP = (int*)(ws + gsrc_pp_o); int* gbP = (int*)(ws + gbase_pp_o); float* gwP = ws + gw_pp_o;
  int* gsB = (int*)(ws + gsrc_bh_o); int* gbB = (int*)(ws + gbase_bh_o); float* gwB = ws + gw_bh_o;
  float* h  = ws + h_o; float* h1 = ws + h1_o; float* h2 = ws + h2_o;
  float* Pp = ws + P_o;
  float* T  = ws + T_o;

  auto pick = [&](int KC)->int{
    int c = NPART;
    while (c > 32 && (size_t)c*KC > T_avail) c >>= 1;
    return c;
  };

  feats_kernel<<<(NPART+255)/256, 256, 0, stream>>>(vel, mass, bh_vel, bh_mass, featsP, bhfeatsP);
  geom_kernel<<<(EPX+255)/256, 256, 0, stream>>>(pos, pos, pp_src, pp_dst, EPX, NPART, 1.f/4.5f, gsP, gbP, gwP);
  geom_kernel<<<(EBX+255)/256, 256, 0, stream>>>(bh_pos, pos, bh_src, bh_dst, EBX, NPART, 1.f/18.f, gsB, gbB, gwB);
  csr_kernel<<<(NPART+1+255)/256, 256, 0, stream>>>(pp_dst, EPX, rsPP);
  csr_kernel<<<(NPART+1+255)/256, 256, 0, stream>>>(bh_dst, EBX, rsBH);

  // run one pp-conv layer (COUT=64) with the new GEMM when chunk >= 128
  auto conv64 = [&](int KC, int CINv, const float* feats_in, const float* W, const float* b,
                    float* dst, int relu) {
    int chunk = pick(KC);
    for (int m0 = 0; m0 < NPART; m0 += chunk) {
      if (CINv == 96) scatter2_kernel<96><<<chunk/2, 128, 0, stream>>>(rsPP, gsP, gbP, gwP, feats_in, T, m0);
      else            scatter2_kernel<64><<<chunk/2, 128, 0, stream>>>(rsPP, gsP, gbP, gwP, feats_in, T, m0);
      if (chunk >= 128) {
        dim3 g(chunk/128, KSPLIT);
        gemm64_kernel<<<g, 256, 0, stream>>>(T, KC, W, Pp, chunk);
        reduce64_kernel<<<(chunk*64+255)/256, 256, 0, stream>>>(Pp, chunk, b, dst, 64, 0, m0, relu);
      } else {
        gemm_kernel<64><<<chunk/32, 256, 0, stream>>>(T, KC, W, b, dst, 64, 0, m0, relu);
      }
    }
  };

  // ---- layer 0: c0 (pp conv, 4->32), cb (bh conv, 4->32), d0 ----
  {
    int KC = 256, chunk = pick(KC);
    for (int m0 = 0; m0 < NPART; m0 += chunk) {
      scatter2_kernel<4><<<chunk/2, 128, 0, stream>>>(rsPP, gsP, gbP, gwP, featsP, T, m0);
      gemm_kernel<32><<<chunk/32, 256, 0, stream>>>(T, KC, W0a, b0a, h, 96, 0, m0, 0);
    }
    for (int m0 = 0; m0 < NPART; m0 += chunk) {
      scatter2_kernel<4><<<chunk/2, 128, 0, stream>>>(rsBH, gsB, gbB, gwB, bhfeatsP, T, m0);
      gemm_kernel<32><<<chunk/32, 256, 0, stream>>>(T, KC, W0b, b0b, h, 96, 32, m0, 0);
    }
    dense_kernel<4,32,0,0,0><<<((size_t)NPART*32+255)/256, 256, 0, stream>>>(featsP, Wd0, bd0, h, 96, 64, nullptr);
  }
  // ---- layer 1: h(96) -> h1 = relu(c1) + relu(d1), 64 ----
  conv64(6144, 96, h, W1, b1, h1, 1);
  dense_kernel<96,64,1,1,0><<<((size_t)NPART*64+255)/256, 256, 0, stream>>>(h, Wd1, bd1, h1, 64, 0, nullptr);
  // ---- layer 2: h1(64) -> h2 = relu(c2) + relu(d2) + h1 ----
  conv64(4096, 64, h1, W2, b2, h2, 1);
  dense_kernel<64,64,1,1,1><<<((size_t)NPART*64+255)/256, 256, 0, stream>>>(h1, Wd2, bd2, h2, 64, 0, h1);
  // ---- layer 3: h2(64) -> out = c3 + d3, 3 ----
  {
    int KC = 4096, chunk = pick(KC);
    for (int m0 = 0; m0 < NPART; m0 += chunk) {
      scatter2_kernel<64><<<chunk/2, 128, 0, stream>>>(rsPP, gsP, gbP, gwP, h2, T, m0);
      int cn = (NPART - m0 < chunk) ? (NPART - m0) : chunk;
      conv3b_kernel<<<cn, 256, 0, stream>>>(T, KC, W3, b3, out, m0, cn);
    }
    dense_kernel<64,3,0,1,0><<<((size_t)NPART*3+255)/256, 256, 0, stream>>>(h2, Wd3, bd3, out, 3, 0, nullptr);
  }
}

// Round 4
// 519.931 us; speedup vs baseline: 7.1177x; 1.1928x over previous
//
#include <hip/hip_runtime.h>
#include <math.h>

#define NPART 8192
#define NBHX  64
#define EPX   300000
#define EBX   160000
#define KSPLIT 8
#define FOUR_OVER_PI 1.27323954473516f

typedef __attribute__((ext_vector_type(8))) short bf16x8;
typedef __attribute__((ext_vector_type(4))) float f32x4;

__device__ __forceinline__ float signf(float x){ return (x>0.f)?1.f:((x<0.f)?-1.f:0.f); }
__device__ __forceinline__ unsigned short f2bf(float f){
  unsigned u = __float_as_uint(f);
  u += 0x7FFFu + ((u >> 16) & 1u);   // RNE
  return (unsigned short)(u >> 16);
}
__device__ __forceinline__ float bf2f(unsigned short h){
  return __uint_as_float(((unsigned)h) << 16);
}

// ---------------- feats build ----------------
__global__ void feats_kernel(const float* __restrict__ vel, const float* __restrict__ mass,
                             const float* __restrict__ bhvel, const float* __restrict__ bhmass,
                             float* __restrict__ feats, float* __restrict__ bhfeats) {
  int i = blockIdx.x*256 + threadIdx.x;
  if (i < NPART) {
    feats[i*4+0]=vel[i*3+0]; feats[i*4+1]=vel[i*3+1]; feats[i*4+2]=vel[i*3+2]; feats[i*4+3]=mass[i];
  }
  if (i < NBHX) {
    bhfeats[i*4+0]=bhvel[i*3+0]; bhfeats[i*4+1]=bhvel[i*3+1]; bhfeats[i*4+2]=bhvel[i*3+2]; bhfeats[i*4+3]=bhmass[i];
  }
}

// ---------------- edge geometry ----------------
__global__ void geom_kernel(const float* __restrict__ ppos, const float* __restrict__ qpos,
                            const int* __restrict__ src, const int* __restrict__ dst,
                            int E, int n_out, float inv_radius,
                            int* __restrict__ gsrc, int* __restrict__ gbase, float* __restrict__ gw) {
  int e = blockIdx.x*256 + threadIdx.x;
  if (e >= E) return;
  int s = src[e], t = dst[e];
  gsrc[e] = s;
  if (t >= n_out) { // padding edge, never referenced via CSR
    gbase[e] = 0;
    for (int j=0;j<8;j++) gw[(size_t)e*8+j] = 0.f;
    return;
  }
  float x = (ppos[s*3+0] - qpos[t*3+0]) * inv_radius;
  float y = (ppos[s*3+1] - qpos[t*3+1]) * inv_radius;
  float z = (ppos[s*3+2] - qpos[t*3+2]) * inv_radius;
  float r2 = x*x + y*y + z*z;
  float w1 = 1.f - r2;
  float win = fminf(fmaxf(w1*w1*w1, 0.f), 1.f);
  const float eps = 1e-8f;
  float sq = r2;
  float nrm = sqrtf(sq);
  float xy = x*x + y*y;
  bool caps = (1.25f*z*z > xy);
  float s_caps = sqrtf(3.f*nrm/(nrm + fabsf(z) + eps));
  float s_side = nrm / sqrtf(xy + eps);
  float sc = caps ? s_caps : s_side;
  bool valid = sq > eps;
  float cx = valid ? x*sc : 0.f;
  float cy = valid ? y*sc : 0.f;
  float cz = valid ? (caps ? signf(z)*nrm : 1.5f*z) : 0.f;
  float rxy = sqrtf(cx*cx + cy*cy);
  bool regA = (cx*cx >= cy*cy);
  float safe_cx = (fabsf(cx) > eps) ? cx : 1.0f;
  float safe_cy = (fabsf(cy) > eps) ? cy : 1.0f;
  float uA = signf(cx)*rxy;
  float vA = uA * FOUR_OVER_PI * atanf(cy/safe_cx);
  float vB = signf(cy)*rxy;
  float uB = vB * FOUR_OVER_PI * atanf(cx/safe_cy);
  bool okxy = rxy > eps;
  float u = okxy ? (regA ? uA : uB) : 0.f;
  float v = okxy ? (regA ? vA : vB) : 0.f;
  float tt[3] = { (u+1.f)*1.5f, (v+1.f)*1.5f, (cz+1.f)*1.5f };
  int i0[3]; float f[3];
#pragma unroll
  for (int ax=0; ax<3; ax++) {
    float tf = floorf(tt[ax]);
    tf = fminf(fmaxf(tf, 0.f), 2.f);
    i0[ax] = (int)tf;
    f[ax] = tt[ax] - tf;
  }
  gbase[e] = (i0[0]*4 + i0[1])*4 + i0[2];
#pragma unroll
  for (int j=0;j<8;j++) {
    float wx = (j&4) ? f[0] : 1.f - f[0];
    float wy = (j&2) ? f[1] : 1.f - f[1];
    float wz = (j&1) ? f[2] : 1.f - f[2];
    gw[(size_t)e*8+j] = win * wx * wy * wz;
  }
}

// ---------------- CSR row offsets (dst sorted non-decreasing) ----------------
__global__ void csr_kernel(const int* __restrict__ dst, int E, int* __restrict__ rs) {
  int n = blockIdx.x*256 + threadIdx.x;
  if (n > NPART) return;
  int lo = 0, hi = E;
  while (lo < hi) { int mid = (lo+hi)>>1; if (dst[mid] < n) lo = mid+1; else hi = mid; }
  rs[n] = lo;
}

// ---------------- W transpose + bf16: WT[64][KC] (rows >= CO zero) ----------------
__global__ void wtrans_kernel(const float* __restrict__ W, int KC, int CO,
                              unsigned short* __restrict__ WT) {
  int idx = blockIdx.x*256 + threadIdx.x;
  if (idx >= 64*KC) return;
  int n = idx / KC, k = idx - n*KC;
  float v = (n < CO) ? W[(size_t)k*CO + n] : 0.f;
  WT[(size_t)n*KC + k] = f2bf(v);
}

// ---------------- scatter: one wave per node, LDS RMW, NO atomics, bf16 out ----------------
template<int CIN>
__global__ __launch_bounds__(128) void scatter2_kernel(
    const int* __restrict__ rs, const int* __restrict__ gsrc, const int* __restrict__ gbase,
    const float* __restrict__ gw, const float* __restrict__ feats,
    unsigned short* __restrict__ T, int m0) {
  constexpr int ROW = 64*CIN;
  __shared__ __align__(16) float Tl[2*ROW];
  const int lane = threadIdx.x & 63;
  const int wid  = threadIdx.x >> 6;
  float* Tw = Tl + wid*ROW;
  const int nodeL = blockIdx.x*2 + wid;
  float4 z4; z4.x=0.f; z4.y=0.f; z4.z=0.f; z4.w=0.f;
  for (int i = lane; i < ROW/4; i += 64) ((float4*)Tw)[i] = z4;
  const int e0 = rs[m0 + nodeL], e1 = rs[m0 + nodeL + 1];
  if constexpr (CIN == 4) {
    const int j = (lane >> 2) & 7;
    const int c = lane & 3;
    const int koff = ((j&4)<<2) | ((j&2)<<1) | (j&1);
    for (int e = e0; e < e1; e++) {
      int s    = gsrc[e];
      int base = gbase[e];
      float w  = gw[(size_t)e*8 + j];
      float F  = feats[s*4 + c];
      if (lane < 32) {
        int a = (base + koff)*4 + c;
        Tw[a] += w * F;
      }
    }
  } else if constexpr (CIN == 96) {
    // lanes 0..47 own channel pair (2l, 2l+1); b64 LDS RMW -> 16 DS ops/edge
    for (int e = e0; e < e1; e++) {
      int s    = gsrc[e];
      int base = gbase[e];
      float4 wA = *(const float4*)(gw + (size_t)e*8);
      float4 wB = *(const float4*)(gw + (size_t)e*8 + 4);
      float2 F;
      if (lane < 48) F = *(const float2*)(feats + (size_t)s*96 + 2*lane);
      float wj[8] = {wA.x,wA.y,wA.z,wA.w,wB.x,wB.y,wB.z,wB.w};
      int a[8];
#pragma unroll
      for (int j=0;j<8;j++) {
        int koff = ((j&4)<<2) | ((j&2)<<1) | (j&1);
        a[j] = (base + koff)*96 + 2*lane;
      }
      if (lane < 48) {
        float2 r[8];
#pragma unroll
        for (int j=0;j<8;j++) r[j] = *(const float2*)(Tw + a[j]);
#pragma unroll
        for (int j=0;j<8;j++) {
          float2 o; o.x = r[j].x + wj[j]*F.x; o.y = r[j].y + wj[j]*F.y;
          *(float2*)(Tw + a[j]) = o;
        }
      }
    }
  } else {
    for (int e = e0; e < e1; e++) {
      int s    = gsrc[e];
      int base = gbase[e];
      float4 wA = *(const float4*)(gw + (size_t)e*8);
      float4 wB = *(const float4*)(gw + (size_t)e*8 + 4);
      float F0 = feats[(size_t)s*CIN + lane];
      float wj0=wA.x, wj1=wA.y, wj2=wA.z, wj3=wA.w, wj4=wB.x, wj5=wB.y, wj6=wB.z, wj7=wB.w;
      int a[8]; float r[8];
#pragma unroll
      for (int j=0;j<8;j++) {
        int koff = ((j&4)<<2) | ((j&2)<<1) | (j&1);
        a[j] = (base + koff)*CIN + lane;
        r[j] = Tw[a[j]];
      }
      Tw[a[0]] = r[0] + wj0*F0;
      Tw[a[1]] = r[1] + wj1*F0;
      Tw[a[2]] = r[2] + wj2*F0;
      Tw[a[3]] = r[3] + wj3*F0;
      Tw[a[4]] = r[4] + wj4*F0;
      Tw[a[5]] = r[5] + wj5*F0;
      Tw[a[6]] = r[6] + wj6*F0;
      Tw[a[7]] = r[7] + wj7*F0;
    }
  }
  // writeout as bf16 (coalesced ushort4 = 8B/lane)
  unsigned short* To = T + (size_t)nodeL*ROW;
  for (int i = lane; i < ROW/4; i += 64) {
    float4 v = ((const float4*)Tw)[i];
    ushort4 o;
    o.x = f2bf(v.x); o.y = f2bf(v.y); o.z = f2bf(v.z); o.w = f2bf(v.w);
    ((ushort4*)To)[i] = o;
  }
}

// ---------------- MFMA bf16 GEMM: P[s][m][0:64] = T[m, ks] . WT^T[ks, 0:64] ----------------
// grid (chunk/128, KSPLIT), 256 thr = 4 waves; wave owns 32 rows x 64 cols.
// A-frag: lane holds T[m0+r][k0+g*8 .. +7]; B-frag: WT[n0+r][k0+g*8 .. +7];
// D: row=(lane>>4)*4+j, col=lane&15  (m92/m97-verified layout).
__global__ __launch_bounds__(256) void gemm_mfma_kernel(
    const unsigned short* __restrict__ T, int KC, const unsigned short* __restrict__ WT,
    float* __restrict__ P, int chunk) {
  const int wid  = threadIdx.x >> 6;
  const int lane = threadIdx.x & 63;
  const int r = lane & 15, g = lane >> 4;
  const int m0 = blockIdx.x*128 + wid*32;
  const int kc_per = KC / KSPLIT;
  const int kb = blockIdx.y * kc_per;
  f32x4 acc[2][4];
#pragma unroll
  for (int h=0;h<2;h++)
#pragma unroll
    for (int n=0;n<4;n++) acc[h][n] = (f32x4){0.f,0.f,0.f,0.f};
  const unsigned short* A0 = T + (size_t)(m0 + r)*KC;
  const unsigned short* A1 = T + (size_t)(m0 + 16 + r)*KC;
  for (int k0 = kb; k0 < kb + kc_per; k0 += 32) {
    int ko = k0 + g*8;
    bf16x8 a0 = *(const bf16x8*)(A0 + ko);
    bf16x8 a1 = *(const bf16x8*)(A1 + ko);
#pragma unroll
    for (int n=0; n<4; n++) {
      bf16x8 b = *(const bf16x8*)(WT + (size_t)(n*16 + r)*KC + ko);
      acc[0][n] = __builtin_amdgcn_mfma_f32_16x16x32_bf16(a0, b, acc[0][n], 0, 0, 0);
      acc[1][n] = __builtin_amdgcn_mfma_f32_16x16x32_bf16(a1, b, acc[1][n], 0, 0, 0);
    }
  }
  float* Pp = P + (size_t)blockIdx.y*chunk*64;
#pragma unroll
  for (int h=0;h<2;h++)
#pragma unroll
    for (int n=0;n<4;n++)
#pragma unroll
      for (int j=0;j<4;j++)
        Pp[(size_t)(m0 + h*16 + g*4 + j)*64 + n*16 + r] = acc[h][n][j];
}

__global__ void reduce64_kernel(const float* __restrict__ P, int chunk,
    const float* __restrict__ b, float* __restrict__ out, int ldo, int coff, int m0, int relu) {
  int idx = blockIdx.x*256 + threadIdx.x;
  if (idx >= chunk*64) return;
  int m = idx >> 6, d = idx & 63;
  float a = b[d];
#pragma unroll
  for (int s=0;s<KSPLIT;s++) a += P[((size_t)s*chunk + m)*64 + d];
  if (relu) a = fmaxf(a, 0.f);
  out[(size_t)(m0+m)*ldo + coff + d] = a;
}

__global__ void reduce3_kernel(const float* __restrict__ P, int chunk,
    const float* __restrict__ b, float* __restrict__ out, int m0) {
  int idx = blockIdx.x*256 + threadIdx.x;
  if (idx >= chunk*3) return;
  int m = idx/3, d = idx - m*3;
  float a = b[d];
#pragma unroll
  for (int s=0;s<KSPLIT;s++) a += P[((size_t)s*chunk + m)*64 + d];
  out[(size_t)(m0+m)*3 + d] = a;
}

// ---------------- small tiled GEMM for layer-0 (COUT=32), bf16 T input ----------------
template<int COUT>
__global__ __launch_bounds__(256) void gemm_kernel(
    const unsigned short* __restrict__ T, int KC, const float* __restrict__ W,
    const float* __restrict__ b, float* __restrict__ out,
    int ldo, int coff, int m0, int relu) {
  constexpr int BM = 32, BK = 32;
  constexpr int NG = 256 / COUT;
  constexpr int RPT = BM / NG;
  __shared__ float Tt[BM*BK];
  __shared__ float Wt[BK*COUT];
  int d = threadIdx.x % COUT;
  int rg = threadIdx.x / COUT;
  float acc[RPT];
#pragma unroll
  for (int i=0;i<RPT;i++) acc[i] = 0.f;
  const unsigned short* Trow = T + (size_t)blockIdx.x*BM*KC;
  for (int k0 = 0; k0 < KC; k0 += BK) {
    {
      int idx = threadIdx.x*4;
      int rr = idx / BK, cc = idx % BK;
      ushort4 v = *(const ushort4*)(Trow + (size_t)rr*KC + k0 + cc);
      Tt[idx+0] = bf2f(v.x); Tt[idx+1] = bf2f(v.y);
      Tt[idx+2] = bf2f(v.z); Tt[idx+3] = bf2f(v.w);
    }
    for (int i = threadIdx.x*4; i < BK*COUT; i += 1024) {
      int rr = i / COUT, cc = i % COUT;
      *(float4*)(&Wt[rr*COUT + cc]) = *(const float4*)(W + (size_t)(k0+rr)*COUT + cc);
    }
    __syncthreads();
#pragma unroll 8
    for (int k2 = 0; k2 < BK; k2++) {
      float wv = Wt[k2*COUT + d];
#pragma unroll
      for (int i=0;i<RPT;i++) acc[i] += Tt[(rg + NG*i)*BK + k2] * wv;
    }
    __syncthreads();
  }
  float bb = b[d];
#pragma unroll
  for (int i=0;i<RPT;i++) {
    float v = acc[i] + bb;
    if (relu) v = fmaxf(v, 0.f);
    int row = m0 + blockIdx.x*BM + rg + NG*i;
    out[(size_t)row*ldo + coff + d] = v;
  }
}

// ---------------- dense (1x1) layers ----------------
template<int CIN, int COUT, int RELU, int ACCUM, int ADDSKIP>
__global__ void dense_kernel(const float* __restrict__ X, const float* __restrict__ Wd,
                             const float* __restrict__ bd, float* __restrict__ out,
                             int ldo, int coff, const float* __restrict__ skip) {
  int idx = blockIdx.x*256 + threadIdx.x;
  if (idx >= NPART*COUT) return;
  int n = idx / COUT, d = idx - n*COUT;
  float acc = bd[d];
  const float* x = X + (size_t)n*CIN;
#pragma unroll 4
  for (int c=0;c<CIN;c++) acc += x[c]*Wd[c*COUT + d];
  if (RELU) acc = fmaxf(acc, 0.f);
  if (ADDSKIP) acc += skip[(size_t)n*COUT + d];
  float* o = out + (size_t)n*ldo + coff + d;
  if (ACCUM) *o += acc; else *o = acc;
}

extern "C" void kernel_launch(void* const* d_in, const int* in_sizes, int n_in,
                              void* d_out, int out_size, void* d_ws, size_t ws_size,
                              hipStream_t stream) {
  const float* pos    = (const float*)d_in[0];
  const float* vel    = (const float*)d_in[1];
  const float* mass   = (const float*)d_in[2];
  const float* bh_pos = (const float*)d_in[3];
  const float* bh_vel = (const float*)d_in[4];
  const float* bh_mass= (const float*)d_in[5];
  const int* pp_src   = (const int*)d_in[6];
  const int* pp_dst   = (const int*)d_in[7];
  const int* bh_src   = (const int*)d_in[8];
  const int* bh_dst   = (const int*)d_in[9];
  const float* W0a=(const float*)d_in[10]; const float* b0a=(const float*)d_in[11];
  const float* Wd0=(const float*)d_in[12]; const float* bd0=(const float*)d_in[13];
  const float* W0b=(const float*)d_in[14]; const float* b0b=(const float*)d_in[15];
  const float* W1 =(const float*)d_in[16]; const float* b1 =(const float*)d_in[17];
  const float* Wd1=(const float*)d_in[18]; const float* bd1=(const float*)d_in[19];
  const float* W2 =(const float*)d_in[20]; const float* b2 =(const float*)d_in[21];
  const float* Wd2=(const float*)d_in[22]; const float* bd2=(const float*)d_in[23];
  const float* W3 =(const float*)d_in[24]; const float* b3 =(const float*)d_in[25];
  const float* Wd3=(const float*)d_in[26]; const float* bd3=(const float*)d_in[27];
  float* out = (float*)d_out;
  char* wsb = (char*)d_ws;

  size_t off = 0;
  auto alloc = [&](size_t nbytes){ size_t o = off; off += (nbytes + 255) & ~((size_t)255); return o; };
  size_t feats_o   = alloc((size_t)NPART*4*4);
  size_t bhfeats_o = alloc((size_t)NBHX*4*4);
  size_t rs_pp_o   = alloc(8256*4);
  size_t rs_bh_o   = alloc(8256*4);
  size_t gsrc_pp_o = alloc((size_t)EPX*4);
  size_t gbase_pp_o= alloc((size_t)EPX*4);
  size_t gw_pp_o   = alloc((size_t)EPX*8*4);
  size_t gsrc_bh_o = alloc((size_t)EBX*4);
  size_t gbase_bh_o= alloc((size_t)EBX*4);
  size_t gw_bh_o   = alloc((size_t)EBX*8*4);
  size_t h_o  = alloc((size_t)NPART*96*4);
  size_t h1_o = alloc((size_t)NPART*64*4);
  size_t h2_o = alloc((size_t)NPART*64*4);
  size_t P_o  = alloc((size_t)KSPLIT*NPART*64*4);
  size_t wt1_o = alloc((size_t)64*6144*2);
  size_t wt2_o = alloc((size_t)64*4096*2);
  size_t wt3_o = alloc((size_t)64*4096*2);
  size_t T_o  = off;
  size_t T_avail = (ws_size > T_o) ? (ws_size - T_o) : 0;

  float* featsP = (float*)(wsb + feats_o); float* bhfeatsP = (float*)(wsb + bhfeats_o);
  int* rsPP = (int*)(wsb + rs_pp_o); int* rsBH = (int*)(wsb + rs_bh_o);
  int* gsP = (int*)(wsb + gsrc_pp_o); int* gbP = (int*)(wsb + gbase_pp_o); float* gwP = (float*)(wsb + gw_pp_o);
  int* gsB = (int*)(wsb + gsrc_bh_o); int* gbB = (int*)(wsb + gbase_bh_o); float* gwB = (float*)(wsb + gw_bh_o);
  float* h  = (float*)(wsb + h_o); float* h1 = (float*)(wsb + h1_o); float* h2 = (float*)(wsb + h2_o);
  float* Pp = (float*)(wsb + P_o);
  unsigned short* WT1 = (unsigned short*)(wsb + wt1_o);
  unsigned short* WT2 = (unsigned short*)(wsb + wt2_o);
  unsigned short* WT3 = (unsigned short*)(wsb + wt3_o);
  unsigned short* T   = (unsigned short*)(wsb + T_o);

  auto pick = [&](int KC)->int{
    int c = NPART;
    while (c > 128 && (size_t)c*KC*2 > T_avail) c >>= 1;
    return c;
  };

  feats_kernel<<<(NPART+255)/256, 256, 0, stream>>>(vel, mass, bh_vel, bh_mass, featsP, bhfeatsP);
  geom_kernel<<<(EPX+255)/256, 256, 0, stream>>>(pos, pos, pp_src, pp_dst, EPX, NPART, 1.f/4.5f, gsP, gbP, gwP);
  geom_kernel<<<(EBX+255)/256, 256, 0, stream>>>(bh_pos, pos, bh_src, bh_dst, EBX, NPART, 1.f/18.f, gsB, gbB, gwB);
  csr_kernel<<<(NPART+1+255)/256, 256, 0, stream>>>(pp_dst, EPX, rsPP);
  csr_kernel<<<(NPART+1+255)/256, 256, 0, stream>>>(bh_dst, EBX, rsBH);
  wtrans_kernel<<<(64*6144+255)/256, 256, 0, stream>>>(W1, 6144, 64, WT1);
  wtrans_kernel<<<(64*4096+255)/256, 256, 0, stream>>>(W2, 4096, 64, WT2);
  wtrans_kernel<<<(64*4096+255)/256, 256, 0, stream>>>(W3, 4096, 3,  WT3);

  // ---- layer 0: c0 (pp conv, 4->32), cb (bh conv, 4->32), d0 ----
  {
    int KC = 256, chunk = pick(KC);
    for (int m0 = 0; m0 < NPART; m0 += chunk) {
      scatter2_kernel<4><<<chunk/2, 128, 0, stream>>>(rsPP, gsP, gbP, gwP, featsP, T, m0);
      gemm_kernel<32><<<chunk/32, 256, 0, stream>>>(T, KC, W0a, b0a, h, 96, 0, m0, 0);
    }
    for (int m0 = 0; m0 < NPART; m0 += chunk) {
      scatter2_kernel<4><<<chunk/2, 128, 0, stream>>>(rsBH, gsB, gbB, gwB, bhfeatsP, T, m0);
      gemm_kernel<32><<<chunk/32, 256, 0, stream>>>(T, KC, W0b, b0b, h, 96, 32, m0, 0);
    }
    dense_kernel<4,32,0,0,0><<<((size_t)NPART*32+255)/256, 256, 0, stream>>>(featsP, Wd0, bd0, h, 96, 64, nullptr);
  }
  // ---- layer 1: h(96) -> h1 = relu(c1) + relu(d1), 64 ----
  {
    int KC = 6144, chunk = pick(KC);
    for (int m0 = 0; m0 < NPART; m0 += chunk) {
      scatter2_kernel<96><<<chunk/2, 128, 0, stream>>>(rsPP, gsP, gbP, gwP, h, T, m0);
      dim3 g(chunk/128, KSPLIT);
      gemm_mfma_kernel<<<g, 256, 0, stream>>>(T, KC, WT1, Pp, chunk);
      reduce64_kernel<<<(chunk*64+255)/256, 256, 0, stream>>>(Pp, chunk, b1, h1, 64, 0, m0, 1);
    }
    dense_kernel<96,64,1,1,0><<<((size_t)NPART*64+255)/256, 256, 0, stream>>>(h, Wd1, bd1, h1, 64, 0, nullptr);
  }
  // ---- layer 2: h1(64) -> h2 = relu(c2) + relu(d2) + h1 ----
  {
    int KC = 4096, chunk = pick(KC);
    for (int m0 = 0; m0 < NPART; m0 += chunk) {
      scatter2_kernel<64><<<chunk/2, 128, 0, stream>>>(rsPP, gsP, gbP, gwP, h1, T, m0);
      dim3 g(chunk/128, KSPLIT);
      gemm_mfma_kernel<<<g, 256, 0, stream>>>(T, KC, WT2, Pp, chunk);
      reduce64_kernel<<<(chunk*64+255)/256, 256, 0, stream>>>(Pp, chunk, b2, h2, 64, 0, m0, 1);
    }
    dense_kernel<64,64,1,1,1><<<((size_t)NPART*64+255)/256, 256, 0, stream>>>(h1, Wd2, bd2, h2, 64, 0, h1);
  }
  // ---- layer 3: h2(64) -> out = c3 + d3, 3  (c3 via padded-N MFMA) ----
  {
    int KC = 4096, chunk = pick(KC);
    for (int m0 = 0; m0 < NPART; m0 += chunk) {
      scatter2_kernel<64><<<chunk/2, 128, 0, stream>>>(rsPP, gsP, gbP, gwP, h2, T, m0);
      dim3 g(chunk/128, KSPLIT);
      gemm_mfma_kernel<<<g, 256, 0, stream>>>(T, KC, WT3, Pp, chunk);
      reduce3_kernel<<<(chunk*3+255)/256, 256, 0, stream>>>(Pp, chunk, b3, out, m0);
    }
    dense_kernel<64,3,0,1,0><<<((size_t)NPART*3+255)/256, 256, 0, stream>>>(h2, Wd3, bd3, out, 3, 0, nullptr);
  }
}

// Round 5
// 511.062 us; speedup vs baseline: 7.2412x; 1.0174x over previous
//
#include <hip/hip_runtime.h>
#include <math.h>

#define NPART 8192
#define NBHX  64
#define EPX   300000
#define EBX   160000
#define KSPLIT 8
#define FOUR_OVER_PI 1.27323954473516f

typedef __attribute__((ext_vector_type(8))) short bf16x8;
typedef __attribute__((ext_vector_type(4))) float f32x4;

__device__ __forceinline__ float signf(float x){ return (x>0.f)?1.f:((x<0.f)?-1.f:0.f); }
__device__ __forceinline__ unsigned short f2bf(float f){
  unsigned u = __float_as_uint(f);
  u += 0x7FFFu + ((u >> 16) & 1u);   // RNE
  return (unsigned short)(u >> 16);
}
__device__ __forceinline__ float bf2f(unsigned short h){
  return __uint_as_float(((unsigned)h) << 16);
}

// ---------------- feats build ----------------
__global__ void feats_kernel(const float* __restrict__ vel, const float* __restrict__ mass,
                             const float* __restrict__ bhvel, const float* __restrict__ bhmass,
                             float* __restrict__ feats, float* __restrict__ bhfeats) {
  int i = blockIdx.x*256 + threadIdx.x;
  if (i < NPART) {
    feats[i*4+0]=vel[i*3+0]; feats[i*4+1]=vel[i*3+1]; feats[i*4+2]=vel[i*3+2]; feats[i*4+3]=mass[i];
  }
  if (i < NBHX) {
    bhfeats[i*4+0]=bhvel[i*3+0]; bhfeats[i*4+1]=bhvel[i*3+1]; bhfeats[i*4+2]=bhvel[i*3+2]; bhfeats[i*4+3]=bhmass[i];
  }
}

// ---------------- edge geometry ----------------
__global__ void geom_kernel(const float* __restrict__ ppos, const float* __restrict__ qpos,
                            const int* __restrict__ src, const int* __restrict__ dst,
                            int E, int n_out, float inv_radius,
                            int* __restrict__ gsrc, int* __restrict__ gbase, float* __restrict__ gw) {
  int e = blockIdx.x*256 + threadIdx.x;
  if (e >= E) return;
  int s = src[e], t = dst[e];
  gsrc[e] = s;
  if (t >= n_out) { // padding edge, never referenced via CSR
    gbase[e] = 0;
    for (int j=0;j<8;j++) gw[(size_t)e*8+j] = 0.f;
    return;
  }
  float x = (ppos[s*3+0] - qpos[t*3+0]) * inv_radius;
  float y = (ppos[s*3+1] - qpos[t*3+1]) * inv_radius;
  float z = (ppos[s*3+2] - qpos[t*3+2]) * inv_radius;
  float r2 = x*x + y*y + z*z;
  float w1 = 1.f - r2;
  float win = fminf(fmaxf(w1*w1*w1, 0.f), 1.f);
  const float eps = 1e-8f;
  float sq = r2;
  float nrm = sqrtf(sq);
  float xy = x*x + y*y;
  bool caps = (1.25f*z*z > xy);
  float s_caps = sqrtf(3.f*nrm/(nrm + fabsf(z) + eps));
  float s_side = nrm / sqrtf(xy + eps);
  float sc = caps ? s_caps : s_side;
  bool valid = sq > eps;
  float cx = valid ? x*sc : 0.f;
  float cy = valid ? y*sc : 0.f;
  float cz = valid ? (caps ? signf(z)*nrm : 1.5f*z) : 0.f;
  float rxy = sqrtf(cx*cx + cy*cy);
  bool regA = (cx*cx >= cy*cy);
  float safe_cx = (fabsf(cx) > eps) ? cx : 1.0f;
  float safe_cy = (fabsf(cy) > eps) ? cy : 1.0f;
  float uA = signf(cx)*rxy;
  float vA = uA * FOUR_OVER_PI * atanf(cy/safe_cx);
  float vB = signf(cy)*rxy;
  float uB = vB * FOUR_OVER_PI * atanf(cx/safe_cy);
  bool okxy = rxy > eps;
  float u = okxy ? (regA ? uA : uB) : 0.f;
  float v = okxy ? (regA ? vA : vB) : 0.f;
  float tt[3] = { (u+1.f)*1.5f, (v+1.f)*1.5f, (cz+1.f)*1.5f };
  int i0[3]; float f[3];
#pragma unroll
  for (int ax=0; ax<3; ax++) {
    float tf = floorf(tt[ax]);
    tf = fminf(fmaxf(tf, 0.f), 2.f);
    i0[ax] = (int)tf;
    f[ax] = tt[ax] - tf;
  }
  gbase[e] = (i0[0]*4 + i0[1])*4 + i0[2];
#pragma unroll
  for (int j=0;j<8;j++) {
    float wx = (j&4) ? f[0] : 1.f - f[0];
    float wy = (j&2) ? f[1] : 1.f - f[1];
    float wz = (j&1) ? f[2] : 1.f - f[2];
    gw[(size_t)e*8+j] = win * wx * wy * wz;
  }
}

// ---------------- CSR row offsets (dst sorted non-decreasing) ----------------
__global__ void csr_kernel(const int* __restrict__ dst, int E, int* __restrict__ rs) {
  int n = blockIdx.x*256 + threadIdx.x;
  if (n > NPART) return;
  int lo = 0, hi = E;
  while (lo < hi) { int mid = (lo+hi)>>1; if (dst[mid] < n) lo = mid+1; else hi = mid; }
  rs[n] = lo;
}

// ---------------- W transpose + bf16: WT[64][KC] (rows >= CO zero) ----------------
__global__ void wtrans_kernel(const float* __restrict__ W, int KC, int CO,
                              unsigned short* __restrict__ WT) {
  int idx = blockIdx.x*256 + threadIdx.x;
  if (idx >= 64*KC) return;
  int n = idx / KC, k = idx - n*KC;
  float v = (n < CO) ? W[(size_t)k*CO + n] : 0.f;
  WT[(size_t)n*KC + k] = f2bf(v);
}

// ---------------- scatter v3: 1 node/block, 2 waves split edges, b128 LDS RMW ----------------
// Each wave accumulates into its private f32 T copy (no cross-wave conflicts);
// within a wave, all 64 lanes touch distinct float4 slots per instruction.
// Manual 1-edge prefetch pipeline hides the gsrc->feats load chain.
template<int CIN>
__global__ __launch_bounds__(128) void scatter3_kernel(
    const int* __restrict__ rs, const int* __restrict__ gsrc, const int* __restrict__ gbase,
    const float* __restrict__ gw, const float* __restrict__ feats,
    unsigned short* __restrict__ T, int m0) {
  constexpr int ROW = 64*CIN;
  constexpr int CHUNKS = CIN/4;           // float4 chunks per corner
  constexpr int PASSES = (8*CHUNKS)/64;   // 2 (CIN=64) or 3 (CIN=96)
  __shared__ __align__(16) float Tl[2*ROW];
  const int lane = threadIdx.x & 63;
  const int wave = threadIdx.x >> 6;
  float* Tw = Tl + wave*ROW;
  const int node = m0 + blockIdx.x;
  float4 z4; z4.x=0.f; z4.y=0.f; z4.z=0.f; z4.w=0.f;
  for (int i = lane; i < ROW/4; i += 64) ((float4*)Tw)[i] = z4;
  // per-lane pass constants
  int jp[PASSES], cp[PASSES], kp[PASSES];
#pragma unroll
  for (int p = 0; p < PASSES; p++) {
    int item = p*64 + lane;
    int j = item / CHUNKS;
    int c4 = item - j*CHUNKS;
    jp[p] = j; cp[p] = c4;
    kp[p] = ((((j&4)<<2) | ((j&2)<<1) | (j&1)))*CIN + c4*4;
  }
  const int e0 = rs[node], e1 = rs[node+1];
  int e = e0 + wave;
  int sN = 0, bN = 0; float wN[PASSES]; float4 fN[PASSES];
  if (e < e1) {
    sN = gsrc[e]; bN = gbase[e];
#pragma unroll
    for (int p=0;p<PASSES;p++) {
      wN[p] = gw[(size_t)e*8 + jp[p]];
      fN[p] = *(const float4*)(feats + (size_t)sN*CIN + cp[p]*4);
    }
  }
  while (e < e1) {
    int bC = bN; float wC[PASSES]; float4 fC[PASSES];
#pragma unroll
    for (int p=0;p<PASSES;p++){ wC[p]=wN[p]; fC[p]=fN[p]; }
    int en = e + 2;
    if (en < e1) {
      sN = gsrc[en]; bN = gbase[en];
#pragma unroll
      for (int p=0;p<PASSES;p++) {
        wN[p] = gw[(size_t)en*8 + jp[p]];
        fN[p] = *(const float4*)(feats + (size_t)sN*CIN + cp[p]*4);
      }
    }
#pragma unroll
    for (int p=0;p<PASSES;p++) {
      int a = bC*CIN + kp[p];
      float4 r = *(const float4*)(Tw + a);
      r.x += wC[p]*fC[p].x; r.y += wC[p]*fC[p].y;
      r.z += wC[p]*fC[p].z; r.w += wC[p]*fC[p].w;
      *(float4*)(Tw + a) = r;
    }
    e = en;
  }
  __syncthreads();
  unsigned short* To = T + (size_t)blockIdx.x*ROW;
  for (int i = threadIdx.x; i < ROW/4; i += 128) {
    float4 a = ((const float4*)Tl)[i];
    float4 b = ((const float4*)(Tl + ROW))[i];
    ushort4 o;
    o.x = f2bf(a.x+b.x); o.y = f2bf(a.y+b.y); o.z = f2bf(a.z+b.z); o.w = f2bf(a.w+b.w);
    ((ushort4*)To)[i] = o;
  }
}

// ---------------- layer-0 scatter (CIN=4): 4 nodes/block, half-wave edge split ----------------
__global__ __launch_bounds__(256) void scatter4_kernel(
    const int* __restrict__ rs, const int* __restrict__ gsrc, const int* __restrict__ gbase,
    const float* __restrict__ gw, const float* __restrict__ feats,
    unsigned short* __restrict__ T, int m0) {
  __shared__ __align__(16) float Tl[4*512];   // per wave: 2 copies x 256
  const int lane = threadIdx.x & 63;
  const int wave = threadIdx.x >> 6;
  float* Tw = Tl + wave*512;
  const int nodeL = blockIdx.x*4 + wave;
  const int node = m0 + nodeL;
  const int half = lane >> 5;
  const int ls = lane & 31;
  const int j = ls >> 2, c = ls & 3;
  const int koff = ((j&4)<<2) | ((j&2)<<1) | (j&1);
  float* Tc = Tw + half*256;
  float4 z4; z4.x=0.f; z4.y=0.f; z4.z=0.f; z4.w=0.f;
  for (int i = lane; i < 128; i += 64) ((float4*)Tw)[i] = z4;
  const int e0 = rs[node], e1 = rs[node+1];
  for (int e = e0 + half; e < e1; e += 2) {
    int s    = gsrc[e];
    int base = gbase[e];
    float w  = gw[(size_t)e*8 + j];
    float F  = feats[s*4 + c];
    int a = (base + koff)*4 + c;
    Tc[a] += w * F;
  }
  // merge two half-wave copies (wave-private; no barrier needed)
  unsigned short* To = T + (size_t)nodeL*256;
  {
    int i = lane;   // 64 float4 chunks
    float4 a = ((const float4*)Tw)[i];
    float4 b = ((const float4*)(Tw + 256))[i];
    ushort4 o;
    o.x = f2bf(a.x+b.x); o.y = f2bf(a.y+b.y); o.z = f2bf(a.z+b.z); o.w = f2bf(a.w+b.w);
    ((ushort4*)To)[i] = o;
  }
}

// ---------------- MFMA bf16 GEMM: P[s][m][0:64] = T[m, ks] . WT^T[ks, 0:64] ----------------
__global__ __launch_bounds__(256) void gemm_mfma_kernel(
    const unsigned short* __restrict__ T, int KC, const unsigned short* __restrict__ WT,
    float* __restrict__ P, int chunk) {
  const int wid  = threadIdx.x >> 6;
  const int lane = threadIdx.x & 63;
  const int r = lane & 15, g = lane >> 4;
  const int m0 = blockIdx.x*128 + wid*32;
  const int kc_per = KC / KSPLIT;
  const int kb = blockIdx.y * kc_per;
  f32x4 acc[2][4];
#pragma unroll
  for (int h=0;h<2;h++)
#pragma unroll
    for (int n=0;n<4;n++) acc[h][n] = (f32x4){0.f,0.f,0.f,0.f};
  const unsigned short* A0 = T + (size_t)(m0 + r)*KC;
  const unsigned short* A1 = T + (size_t)(m0 + 16 + r)*KC;
  for (int k0 = kb; k0 < kb + kc_per; k0 += 32) {
    int ko = k0 + g*8;
    bf16x8 a0 = *(const bf16x8*)(A0 + ko);
    bf16x8 a1 = *(const bf16x8*)(A1 + ko);
#pragma unroll
    for (int n=0; n<4; n++) {
      bf16x8 b = *(const bf16x8*)(WT + (size_t)(n*16 + r)*KC + ko);
      acc[0][n] = __builtin_amdgcn_mfma_f32_16x16x32_bf16(a0, b, acc[0][n], 0, 0, 0);
      acc[1][n] = __builtin_amdgcn_mfma_f32_16x16x32_bf16(a1, b, acc[1][n], 0, 0, 0);
    }
  }
  float* Pp = P + (size_t)blockIdx.y*chunk*64;
#pragma unroll
  for (int h=0;h<2;h++)
#pragma unroll
    for (int n=0;n<4;n++)
#pragma unroll
      for (int j=0;j<4;j++)
        Pp[(size_t)(m0 + h*16 + g*4 + j)*64 + n*16 + r] = acc[h][n][j];
}

__global__ void reduce64_kernel(const float* __restrict__ P, int chunk,
    const float* __restrict__ b, float* __restrict__ out, int ldo, int coff, int m0, int relu) {
  int idx = blockIdx.x*256 + threadIdx.x;
  if (idx >= chunk*64) return;
  int m = idx >> 6, d = idx & 63;
  float a = b[d];
#pragma unroll
  for (int s=0;s<KSPLIT;s++) a += P[((size_t)s*chunk + m)*64 + d];
  if (relu) a = fmaxf(a, 0.f);
  out[(size_t)(m0+m)*ldo + coff + d] = a;
}

__global__ void reduce3_kernel(const float* __restrict__ P, int chunk,
    const float* __restrict__ b, float* __restrict__ out, int m0) {
  int idx = blockIdx.x*256 + threadIdx.x;
  if (idx >= chunk*3) return;
  int m = idx/3, d = idx - m*3;
  float a = b[d];
#pragma unroll
  for (int s=0;s<KSPLIT;s++) a += P[((size_t)s*chunk + m)*64 + d];
  out[(size_t)(m0+m)*3 + d] = a;
}

// ---------------- small tiled GEMM for layer-0 (COUT=32), bf16 T input ----------------
template<int COUT>
__global__ __launch_bounds__(256) void gemm_kernel(
    const unsigned short* __restrict__ T, int KC, const float* __restrict__ W,
    const float* __restrict__ b, float* __restrict__ out,
    int ldo, int coff, int m0, int relu) {
  constexpr int BM = 32, BK = 32;
  constexpr int NG = 256 / COUT;
  constexpr int RPT = BM / NG;
  __shared__ float Tt[BM*BK];
  __shared__ float Wt[BK*COUT];
  int d = threadIdx.x % COUT;
  int rg = threadIdx.x / COUT;
  float acc[RPT];
#pragma unroll
  for (int i=0;i<RPT;i++) acc[i] = 0.f;
  const unsigned short* Trow = T + (size_t)blockIdx.x*BM*KC;
  for (int k0 = 0; k0 < KC; k0 += BK) {
    {
      int idx = threadIdx.x*4;
      int rr = idx / BK, cc = idx % BK;
      ushort4 v = *(const ushort4*)(Trow + (size_t)rr*KC + k0 + cc);
      Tt[idx+0] = bf2f(v.x); Tt[idx+1] = bf2f(v.y);
      Tt[idx+2] = bf2f(v.z); Tt[idx+3] = bf2f(v.w);
    }
    for (int i = threadIdx.x*4; i < BK*COUT; i += 1024) {
      int rr = i / COUT, cc = i % COUT;
      *(float4*)(&Wt[rr*COUT + cc]) = *(const float4*)(W + (size_t)(k0+rr)*COUT + cc);
    }
    __syncthreads();
#pragma unroll 8
    for (int k2 = 0; k2 < BK; k2++) {
      float wv = Wt[k2*COUT + d];
#pragma unroll
      for (int i=0;i<RPT;i++) acc[i] += Tt[(rg + NG*i)*BK + k2] * wv;
    }
    __syncthreads();
  }
  float bb = b[d];
#pragma unroll
  for (int i=0;i<RPT;i++) {
    float v = acc[i] + bb;
    if (relu) v = fmaxf(v, 0.f);
    int row = m0 + blockIdx.x*BM + rg + NG*i;
    out[(size_t)row*ldo + coff + d] = v;
  }
}

// ---------------- dense (1x1) layers ----------------
template<int CIN, int COUT, int RELU, int ACCUM, int ADDSKIP>
__global__ void dense_kernel(const float* __restrict__ X, const float* __restrict__ Wd,
                             const float* __restrict__ bd, float* __restrict__ out,
                             int ldo, int coff, const float* __restrict__ skip) {
  int idx = blockIdx.x*256 + threadIdx.x;
  if (idx >= NPART*COUT) return;
  int n = idx / COUT, d = idx - n*COUT;
  float acc = bd[d];
  const float* x = X + (size_t)n*CIN;
#pragma unroll 4
  for (int c=0;c<CIN;c++) acc += x[c]*Wd[c*COUT + d];
  if (RELU) acc = fmaxf(acc, 0.f);
  if (ADDSKIP) acc += skip[(size_t)n*COUT + d];
  float* o = out + (size_t)n*ldo + coff + d;
  if (ACCUM) *o += acc; else *o = acc;
}

extern "C" void kernel_launch(void* const* d_in, const int* in_sizes, int n_in,
                              void* d_out, int out_size, void* d_ws, size_t ws_size,
                              hipStream_t stream) {
  const float* pos    = (const float*)d_in[0];
  const float* vel    = (const float*)d_in[1];
  const float* mass   = (const float*)d_in[2];
  const float* bh_pos = (const float*)d_in[3];
  const float* bh_vel = (const float*)d_in[4];
  const float* bh_mass= (const float*)d_in[5];
  const int* pp_src   = (const int*)d_in[6];
  const int* pp_dst   = (const int*)d_in[7];
  const int* bh_src   = (const int*)d_in[8];
  const int* bh_dst   = (const int*)d_in[9];
  const float* W0a=(const float*)d_in[10]; const float* b0a=(const float*)d_in[11];
  const float* Wd0=(const float*)d_in[12]; const float* bd0=(const float*)d_in[13];
  const float* W0b=(const float*)d_in[14]; const float* b0b=(const float*)d_in[15];
  const float* W1 =(const float*)d_in[16]; const float* b1 =(const float*)d_in[17];
  const float* Wd1=(const float*)d_in[18]; const float* bd1=(const float*)d_in[19];
  const float* W2 =(const float*)d_in[20]; const float* b2 =(const float*)d_in[21];
  const float* Wd2=(const float*)d_in[22]; const float* bd2=(const float*)d_in[23];
  const float* W3 =(const float*)d_in[24]; const float* b3 =(const float*)d_in[25];
  const float* Wd3=(const float*)d_in[26]; const float* bd3=(const float*)d_in[27];
  float* out = (float*)d_out;
  char* wsb = (char*)d_ws;

  size_t off = 0;
  auto alloc = [&](size_t nbytes){ size_t o = off; off += (nbytes + 255) & ~((size_t)255); return o; };
  size_t feats_o   = alloc((size_t)NPART*4*4);
  size_t bhfeats_o = alloc((size_t)NBHX*4*4);
  size_t rs_pp_o   = alloc(8256*4);
  size_t rs_bh_o   = alloc(8256*4);
  size_t gsrc_pp_o = alloc((size_t)EPX*4);
  size_t gbase_pp_o= alloc((size_t)EPX*4);
  size_t gw_pp_o   = alloc((size_t)EPX*8*4);
  size_t gsrc_bh_o = alloc((size_t)EBX*4);
  size_t gbase_bh_o= alloc((size_t)EBX*4);
  size_t gw_bh_o   = alloc((size_t)EBX*8*4);
  size_t h_o  = alloc((size_t)NPART*96*4);
  size_t h1_o = alloc((size_t)NPART*64*4);
  size_t h2_o = alloc((size_t)NPART*64*4);
  size_t P_o  = alloc((size_t)KSPLIT*NPART*64*4);
  size_t wt1_o = alloc((size_t)64*6144*2);
  size_t wt2_o = alloc((size_t)64*4096*2);
  size_t wt3_o = alloc((size_t)64*4096*2);
  size_t T_o  = off;
  size_t T_avail = (ws_size > T_o) ? (ws_size - T_o) : 0;

  float* featsP = (float*)(wsb + feats_o); float* bhfeatsP = (float*)(wsb + bhfeats_o);
  int* rsPP = (int*)(wsb + rs_pp_o); int* rsBH = (int*)(wsb + rs_bh_o);
  int* gsP = (int*)(wsb + gsrc_pp_o); int* gbP = (int*)(wsb + gbase_pp_o); float* gwP = (float*)(wsb + gw_pp_o);
  int* gsB = (int*)(wsb + gsrc_bh_o); int* gbB = (int*)(wsb + gbase_bh_o); float* gwB = (float*)(wsb + gw_bh_o);
  float* h  = (float*)(wsb + h_o); float* h1 = (float*)(wsb + h1_o); float* h2 = (float*)(wsb + h2_o);
  float* Pp = (float*)(wsb + P_o);
  unsigned short* WT1 = (unsigned short*)(wsb + wt1_o);
  unsigned short* WT2 = (unsigned short*)(wsb + wt2_o);
  unsigned short* WT3 = (unsigned short*)(wsb + wt3_o);
  unsigned short* T   = (unsigned short*)(wsb + T_o);

  auto pick = [&](int KC)->int{
    int c = NPART;
    while (c > 128 && (size_t)c*KC*2 > T_avail) c >>= 1;
    return c;
  };

  feats_kernel<<<(NPART+255)/256, 256, 0, stream>>>(vel, mass, bh_vel, bh_mass, featsP, bhfeatsP);
  geom_kernel<<<(EPX+255)/256, 256, 0, stream>>>(pos, pos, pp_src, pp_dst, EPX, NPART, 1.f/4.5f, gsP, gbP, gwP);
  geom_kernel<<<(EBX+255)/256, 256, 0, stream>>>(bh_pos, pos, bh_src, bh_dst, EBX, NPART, 1.f/18.f, gsB, gbB, gwB);
  csr_kernel<<<(NPART+1+255)/256, 256, 0, stream>>>(pp_dst, EPX, rsPP);
  csr_kernel<<<(NPART+1+255)/256, 256, 0, stream>>>(bh_dst, EBX, rsBH);
  wtrans_kernel<<<(64*6144+255)/256, 256, 0, stream>>>(W1, 6144, 64, WT1);
  wtrans_kernel<<<(64*4096+255)/256, 256, 0, stream>>>(W2, 4096, 64, WT2);
  wtrans_kernel<<<(64*4096+255)/256, 256, 0, stream>>>(W3, 4096, 3,  WT3);

  // ---- layer 0: c0 (pp conv, 4->32), cb (bh conv, 4->32), d0 ----
  {
    int KC = 256, chunk = pick(KC);
    for (int m0 = 0; m0 < NPART; m0 += chunk) {
      scatter4_kernel<<<chunk/4, 256, 0, stream>>>(rsPP, gsP, gbP, gwP, featsP, T, m0);
      gemm_kernel<32><<<chunk/32, 256, 0, stream>>>(T, KC, W0a, b0a, h, 96, 0, m0, 0);
    }
    for (int m0 = 0; m0 < NPART; m0 += chunk) {
      scatter4_kernel<<<chunk/4, 256, 0, stream>>>(rsBH, gsB, gbB, gwB, bhfeatsP, T, m0);
      gemm_kernel<32><<<chunk/32, 256, 0, stream>>>(T, KC, W0b, b0b, h, 96, 32, m0, 0);
    }
    dense_kernel<4,32,0,0,0><<<((size_t)NPART*32+255)/256, 256, 0, stream>>>(featsP, Wd0, bd0, h, 96, 64, nullptr);
  }
  // ---- layer 1: h(96) -> h1 = relu(c1) + relu(d1), 64 ----
  {
    int KC = 6144, chunk = pick(KC);
    for (int m0 = 0; m0 < NPART; m0 += chunk) {
      scatter3_kernel<96><<<chunk, 128, 0, stream>>>(rsPP, gsP, gbP, gwP, h, T, m0);
      dim3 g(chunk/128, KSPLIT);
      gemm_mfma_kernel<<<g, 256, 0, stream>>>(T, KC, WT1, Pp, chunk);
      reduce64_kernel<<<(chunk*64+255)/256, 256, 0, stream>>>(Pp, chunk, b1, h1, 64, 0, m0, 1);
    }
    dense_kernel<96,64,1,1,0><<<((size_t)NPART*64+255)/256, 256, 0, stream>>>(h, Wd1, bd1, h1, 64, 0, nullptr);
  }
  // ---- layer 2: h1(64) -> h2 = relu(c2) + relu(d2) + h1 ----
  {
    int KC = 4096, chunk = pick(KC);
    for (int m0 = 0; m0 < NPART; m0 += chunk) {
      scatter3_kernel<64><<<chunk, 128, 0, stream>>>(rsPP, gsP, gbP, gwP, h1, T, m0);
      dim3 g(chunk/128, KSPLIT);
      gemm_mfma_kernel<<<g, 256, 0, stream>>>(T, KC, WT2, Pp, chunk);
      reduce64_kernel<<<(chunk*64+255)/256, 256, 0, stream>>>(Pp, chunk, b2, h2, 64, 0, m0, 1);
    }
    dense_kernel<64,64,1,1,1><<<((size_t)NPART*64+255)/256, 256, 0, stream>>>(h1, Wd2, bd2, h2, 64, 0, h1);
  }
  // ---- layer 3: h2(64) -> out = c3 + d3, 3  (c3 via padded-N MFMA) ----
  {
    int KC = 4096, chunk = pick(KC);
    for (int m0 = 0; m0 < NPART; m0 += chunk) {
      scatter3_kernel<64><<<chunk, 128, 0, stream>>>(rsPP, gsP, gbP, gwP, h2, T, m0);
      dim3 g(chunk/128, KSPLIT);
      gemm_mfma_kernel<<<g, 256, 0, stream>>>(T, KC, WT3, Pp, chunk);
      reduce3_kernel<<<(chunk*3+255)/256, 256, 0, stream>>>(Pp, chunk, b3, out, m0);
    }
    dense_kernel<64,3,0,1,0><<<((size_t)NPART*3+255)/256, 256, 0, stream>>>(h2, Wd3, bd3, out, 3, 0, nullptr);
  }
}

// Round 6
// 274.832 us; speedup vs baseline: 13.4653x; 1.8595x over previous
//
#include <hip/hip_runtime.h>
#include <math.h>

#define NPART 8192
#define NBHX  64
#define EPX   300000
#define EBX   160000
#define FOUR_OVER_PI 1.27323954473516f

typedef __attribute__((ext_vector_type(8))) short bf16x8;
typedef __attribute__((ext_vector_type(4))) float f32x4;

__device__ __forceinline__ float signf(float x){ return (x>0.f)?1.f:((x<0.f)?-1.f:0.f); }
__device__ __forceinline__ unsigned short f2bf(float f){
  unsigned u = __float_as_uint(f);
  u += 0x7FFFu + ((u >> 16) & 1u);   // RNE
  return (unsigned short)(u >> 16);
}
__device__ __forceinline__ float bf2f(unsigned short h){
  return __uint_as_float(((unsigned)h) << 16);
}

// ---------------- feats build ----------------
__global__ void feats_kernel(const float* __restrict__ vel, const float* __restrict__ mass,
                             const float* __restrict__ bhvel, const float* __restrict__ bhmass,
                             float* __restrict__ feats, float* __restrict__ bhfeats) {
  int i = blockIdx.x*256 + threadIdx.x;
  if (i < NPART) {
    feats[i*4+0]=vel[i*3+0]; feats[i*4+1]=vel[i*3+1]; feats[i*4+2]=vel[i*3+2]; feats[i*4+3]=mass[i];
  }
  if (i < NBHX) {
    bhfeats[i*4+0]=bhvel[i*3+0]; bhfeats[i*4+1]=bhvel[i*3+1]; bhfeats[i*4+2]=bhvel[i*3+2]; bhfeats[i*4+3]=bhmass[i];
  }
}

// ---------------- edge geometry ----------------
__global__ void geom_kernel(const float* __restrict__ ppos, const float* __restrict__ qpos,
                            const int* __restrict__ src, const int* __restrict__ dst,
                            int E, int n_out, float inv_radius,
                            int* __restrict__ gsrc, int* __restrict__ gbase, float* __restrict__ gw) {
  int e = blockIdx.x*256 + threadIdx.x;
  if (e >= E) return;
  int s = src[e], t = dst[e];
  gsrc[e] = s;
  if (t >= n_out) { // padding edge, never referenced via CSR
    gbase[e] = 0;
    for (int j=0;j<8;j++) gw[(size_t)e*8+j] = 0.f;
    return;
  }
  float x = (ppos[s*3+0] - qpos[t*3+0]) * inv_radius;
  float y = (ppos[s*3+1] - qpos[t*3+1]) * inv_radius;
  float z = (ppos[s*3+2] - qpos[t*3+2]) * inv_radius;
  float r2 = x*x + y*y + z*z;
  float w1 = 1.f - r2;
  float win = fminf(fmaxf(w1*w1*w1, 0.f), 1.f);
  const float eps = 1e-8f;
  float sq = r2;
  float nrm = sqrtf(sq);
  float xy = x*x + y*y;
  bool caps = (1.25f*z*z > xy);
  float s_caps = sqrtf(3.f*nrm/(nrm + fabsf(z) + eps));
  float s_side = nrm / sqrtf(xy + eps);
  float sc = caps ? s_caps : s_side;
  bool valid = sq > eps;
  float cx = valid ? x*sc : 0.f;
  float cy = valid ? y*sc : 0.f;
  float cz = valid ? (caps ? signf(z)*nrm : 1.5f*z) : 0.f;
  float rxy = sqrtf(cx*cx + cy*cy);
  bool regA = (cx*cx >= cy*cy);
  float safe_cx = (fabsf(cx) > eps) ? cx : 1.0f;
  float safe_cy = (fabsf(cy) > eps) ? cy : 1.0f;
  float uA = signf(cx)*rxy;
  float vA = uA * FOUR_OVER_PI * atanf(cy/safe_cx);
  float vB = signf(cy)*rxy;
  float uB = vB * FOUR_OVER_PI * atanf(cx/safe_cy);
  bool okxy = rxy > eps;
  float u = okxy ? (regA ? uA : uB) : 0.f;
  float v = okxy ? (regA ? vA : vB) : 0.f;
  float tt[3] = { (u+1.f)*1.5f, (v+1.f)*1.5f, (cz+1.f)*1.5f };
  int i0[3]; float f[3];
#pragma unroll
  for (int ax=0; ax<3; ax++) {
    float tf = floorf(tt[ax]);
    tf = fminf(fmaxf(tf, 0.f), 2.f);
    i0[ax] = (int)tf;
    f[ax] = tt[ax] - tf;
  }
  gbase[e] = (i0[0]*4 + i0[1])*4 + i0[2];
#pragma unroll
  for (int j=0;j<8;j++) {
    float wx = (j&4) ? f[0] : 1.f - f[0];
    float wy = (j&2) ? f[1] : 1.f - f[1];
    float wz = (j&1) ? f[2] : 1.f - f[2];
    gw[(size_t)e*8+j] = win * wx * wy * wz;
  }
}

// ---------------- CSR row offsets (dst sorted non-decreasing) ----------------
__global__ void csr_kernel(const int* __restrict__ dst, int E, int* __restrict__ rs) {
  int n = blockIdx.x*256 + threadIdx.x;
  if (n > NPART) return;
  int lo = 0, hi = E;
  while (lo < hi) { int mid = (lo+hi)>>1; if (dst[mid] < n) lo = mid+1; else hi = mid; }
  rs[n] = lo;
}

// ---------------- BT build: BT[(k*DP+d)][c] = W[k][c][d] (bf16, zero-padded d) ----------------
__global__ void wtransY_kernel(const float* __restrict__ W, int KC, int CO, int DP,
                               unsigned short* __restrict__ BT) {
  int idx = blockIdx.x*256 + threadIdx.x;
  int N = 64*DP;
  if (idx >= N*KC) return;
  int n = idx / KC, c = idx - n*KC;
  int k = n / DP, d = n - k*DP;
  float v = (d < CO) ? W[((size_t)k*KC + c)*CO + d] : 0.f;
  BT[idx] = f2bf(v);
}

// ---------------- Y0[s][k][d32] = feats4[s] . W0[k][:,d]  (K=4, VALU) ----------------
__global__ void y0_kernel(const float* __restrict__ feats4, const float* __restrict__ W0,
                          int NS, unsigned short* __restrict__ Y0) {
  int idx = blockIdx.x*256 + threadIdx.x;
  if (idx >= NS*256) return;
  int oct = idx & 3, k = (idx>>2) & 63, s = idx >> 8;
  float4 f = *(const float4*)(feats4 + (size_t)s*4);
  const float* w = W0 + (size_t)k*128 + oct*8;  // W0[k][c][d] = k*128 + c*32 + d
  unsigned short o[8];
#pragma unroll
  for (int i=0;i<8;i++) {
    float v = f.x*w[i] + f.y*w[32+i] + f.z*w[64+i] + f.w*w[96+i];
    o[i] = f2bf(v);
  }
  uint4 u;
  u.x = (unsigned)o[0] | ((unsigned)o[1]<<16);
  u.y = (unsigned)o[2] | ((unsigned)o[3]<<16);
  u.z = (unsigned)o[4] | ((unsigned)o[5]<<16);
  u.w = (unsigned)o[6] | ((unsigned)o[7]<<16);
  *(uint4*)(Y0 + ((size_t)s*64 + k)*32 + oct*8) = u;
}

// ---------------- MFMA GEMM: Y[m][n] = A[m][:KC] . BT[n][:KC]  (bf16 out) ----------------
__global__ __launch_bounds__(256) void gemm_y_kernel(
    const unsigned short* __restrict__ A, const unsigned short* __restrict__ BT,
    int KC, int Ntot, unsigned short* __restrict__ Y) {
  const int wid  = threadIdx.x >> 6;
  const int lane = threadIdx.x & 63;
  const int r = lane & 15, g = lane >> 4;
  const int m0 = blockIdx.x*128 + wid*32;
  const int n0 = blockIdx.y*64;
  f32x4 acc[2][4];
#pragma unroll
  for (int h=0;h<2;h++)
#pragma unroll
    for (int n=0;n<4;n++) acc[h][n] = (f32x4){0.f,0.f,0.f,0.f};
  const unsigned short* A0 = A + (size_t)(m0 + r)*KC;
  const unsigned short* A1 = A + (size_t)(m0 + 16 + r)*KC;
  for (int k0 = 0; k0 < KC; k0 += 32) {
    int ko = k0 + g*8;
    bf16x8 a0 = *(const bf16x8*)(A0 + ko);
    bf16x8 a1 = *(const bf16x8*)(A1 + ko);
#pragma unroll
    for (int n=0; n<4; n++) {
      bf16x8 b = *(const bf16x8*)(BT + (size_t)(n0 + n*16 + r)*KC + ko);
      acc[0][n] = __builtin_amdgcn_mfma_f32_16x16x32_bf16(a0, b, acc[0][n], 0, 0, 0);
      acc[1][n] = __builtin_amdgcn_mfma_f32_16x16x32_bf16(a1, b, acc[1][n], 0, 0, 0);
    }
  }
#pragma unroll
  for (int h=0;h<2;h++)
#pragma unroll
    for (int n=0;n<4;n++)
#pragma unroll
      for (int j=0;j<4;j++)
        Y[(size_t)(m0 + h*16 + g*4 + j)*Ntot + n0 + n*16 + r] = f2bf(acc[h][n][j]);
}

// ---------------- layer-0 fused gather (pp d32 + bh d32 + dense d32) ----------------
__global__ __launch_bounds__(256) void gather_l0_kernel(
    const int* __restrict__ rsP, const int* __restrict__ gsP, const int* __restrict__ gbP, const float* __restrict__ gwP,
    const int* __restrict__ rsB, const int* __restrict__ gsB, const int* __restrict__ gbB, const float* __restrict__ gwB,
    const unsigned short* __restrict__ Y0a, const unsigned short* __restrict__ Y0b,
    const float* __restrict__ feats4, const float* __restrict__ Wd0, const float* __restrict__ bd0,
    const float* __restrict__ b0a, const float* __restrict__ b0b,
    float* __restrict__ hf, unsigned short* __restrict__ hb) {
  const int node = blockIdx.x*4 + (threadIdx.x >> 6);
  const int lane = threadIdx.x & 63;
  const int e2 = lane >> 5, d = lane & 31;
  float acc0 = 0.f, acc1 = 0.f;
  {
    int e0 = rsP[node], e1 = rsP[node+1];
    for (int e = e0; e < e1; e += 2) {
      int ee = e + e2;
      bool v = ee < e1;
      int ix = v ? ee : e;
      int s = gsP[ix], base = gbP[ix];
      const unsigned short* yr = Y0a + ((size_t)s*64 + base)*32 + d;
      const float* gwp = gwP + (size_t)ix*8;
      float yv[8];
#pragma unroll
      for (int j=0;j<8;j++) {
        const int koff = ((j&4)<<2)|((j&2)<<1)|(j&1);
        yv[j] = bf2f(yr[koff*32]);
      }
#pragma unroll
      for (int j=0;j<8;j++) acc0 += (v ? gwp[j] : 0.f) * yv[j];
    }
  }
  acc0 += __shfl_down(acc0, 32);
  {
    int e0 = rsB[node], e1 = rsB[node+1];
    for (int e = e0; e < e1; e += 2) {
      int ee = e + e2;
      bool v = ee < e1;
      int ix = v ? ee : e;
      int s = gsB[ix], base = gbB[ix];
      const unsigned short* yr = Y0b + ((size_t)s*64 + base)*32 + d;
      const float* gwp = gwB + (size_t)ix*8;
      float yv[8];
#pragma unroll
      for (int j=0;j<8;j++) {
        const int koff = ((j&4)<<2)|((j&2)<<1)|(j&1);
        yv[j] = bf2f(yr[koff*32]);
      }
#pragma unroll
      for (int j=0;j<8;j++) acc1 += (v ? gwp[j] : 0.f) * yv[j];
    }
  }
  acc1 += __shfl_down(acc1, 32);
  // dense d0 (lanes 0..31 meaningful)
  float4 f = *(const float4*)(feats4 + (size_t)node*4);
  float dd = bd0[d] + f.x*Wd0[d] + f.y*Wd0[32+d] + f.z*Wd0[64+d] + f.w*Wd0[96+d];
  if (lane < 32) {
    float c0 = acc0 + b0a[d];
    float cb = acc1 + b0b[d];
    size_t o = (size_t)node*96;
    hf[o + d]      = c0;  hb[o + d]      = f2bf(c0);
    hf[o + 32 + d] = cb;  hb[o + 32 + d] = f2bf(cb);
    hf[o + 64 + d] = dd;  hb[o + 64 + d] = f2bf(dd);
  }
}

// ---------------- fused conv-gather + dense + relu (+skip), d=64 ----------------
template<int DCIN, bool ADDSKIP>
__global__ __launch_bounds__(256) void gather64_kernel(
    const int* __restrict__ rs, const int* __restrict__ gsrc, const int* __restrict__ gbase,
    const float* __restrict__ gw, const unsigned short* __restrict__ Y,
    const float* __restrict__ Xf, const float* __restrict__ Wd, const float* __restrict__ bd,
    const float* __restrict__ bconv, const float* __restrict__ skip,
    float* __restrict__ outf, unsigned short* __restrict__ outb) {
  const int node = blockIdx.x*4 + (threadIdx.x >> 6);
  const int lane = threadIdx.x & 63;
  float acc = 0.f;
  const int e0 = rs[node], e1 = rs[node+1];
  int e = e0;
  for (; e + 2 <= e1; e += 2) {
    int sA = gsrc[e],   bA = gbase[e];
    int sB = gsrc[e+1], bB = gbase[e+1];
    const float* gA = gw + (size_t)e*8;
    const unsigned short* yA = Y + ((size_t)sA*64 + bA)*64 + lane;
    const unsigned short* yB = Y + ((size_t)sB*64 + bB)*64 + lane;
    float yv[16];
#pragma unroll
    for (int j=0;j<8;j++) {
      const int koff = ((j&4)<<2)|((j&2)<<1)|(j&1);
      yv[j]   = bf2f(yA[koff*64]);
      yv[8+j] = bf2f(yB[koff*64]);
    }
#pragma unroll
    for (int j=0;j<8;j++) acc += gA[j]*yv[j] + gA[8+j]*yv[8+j];
  }
  if (e < e1) {
    int sA = gsrc[e], bA = gbase[e];
    const float* gA = gw + (size_t)e*8;
    const unsigned short* yA = Y + ((size_t)sA*64 + bA)*64 + lane;
#pragma unroll
    for (int j=0;j<8;j++) {
      const int koff = ((j&4)<<2)|((j&2)<<1)|(j&1);
      acc += gA[j] * bf2f(yA[koff*64]);
    }
  }
  // dense branch
  float dd = bd[lane];
  const float* x = Xf + (size_t)node*DCIN;
#pragma unroll 8
  for (int c=0;c<DCIN;c++) dd += x[c]*Wd[c*64 + lane];
  float conv = fmaxf(acc + bconv[lane], 0.f);
  dd = fmaxf(dd, 0.f);
  float val = conv + dd;
  if (ADDSKIP) val += skip[(size_t)node*64 + lane];
  outf[(size_t)node*64 + lane] = val;
  outb[(size_t)node*64 + lane] = f2bf(val);
}

// ---------------- layer-3 gather (d=3): lane=(e2,j,dd4), shfl reduce ----------------
__global__ __launch_bounds__(256) void gather3_kernel(
    const int* __restrict__ rs, const int* __restrict__ gsrc, const int* __restrict__ gbase,
    const float* __restrict__ gw, const unsigned short* __restrict__ Y3,
    const float* __restrict__ h2f, const float* __restrict__ Wd3, const float* __restrict__ bd3,
    const float* __restrict__ b3, float* __restrict__ out) {
  const int node = blockIdx.x*4 + (threadIdx.x >> 6);
  const int lane = threadIdx.x & 63;
  const int e2 = lane >> 5, j = (lane >> 2) & 7, dd = lane & 3;
  const int koff = ((j&4)<<2)|((j&2)<<1)|(j&1);
  float acc = 0.f;
  const int e0 = rs[node], e1 = rs[node+1];
  for (int e = e0; e < e1; e += 2) {
    int ee = e + e2;
    bool v = ee < e1;
    int ix = v ? ee : e;
    int s = gsrc[ix], base = gbase[ix];
    float w = v ? gw[(size_t)ix*8 + j] : 0.f;
    acc += w * bf2f(Y3[((size_t)s*64 + base + koff)*4 + dd]);
  }
  acc += __shfl_xor(acc, 4);
  acc += __shfl_xor(acc, 8);
  acc += __shfl_xor(acc, 16);
  acc += __shfl_down(acc, 32);
  if (lane < 3) {   // j=0, e2=0, dd=lane
    float d3 = bd3[lane];
    const float* x = h2f + (size_t)node*64;
#pragma unroll 8
    for (int c=0;c<64;c++) d3 += x[c]*Wd3[c*3 + lane];
    out[(size_t)node*3 + lane] = acc + b3[lane] + d3;
  }
}

extern "C" void kernel_launch(void* const* d_in, const int* in_sizes, int n_in,
                              void* d_out, int out_size, void* d_ws, size_t ws_size,
                              hipStream_t stream) {
  const float* pos    = (const float*)d_in[0];
  const float* vel    = (const float*)d_in[1];
  const float* mass   = (const float*)d_in[2];
  const float* bh_pos = (const float*)d_in[3];
  const float* bh_vel = (const float*)d_in[4];
  const float* bh_mass= (const float*)d_in[5];
  const int* pp_src   = (const int*)d_in[6];
  const int* pp_dst   = (const int*)d_in[7];
  const int* bh_src   = (const int*)d_in[8];
  const int* bh_dst   = (const int*)d_in[9];
  const float* W0a=(const float*)d_in[10]; const float* b0a=(const float*)d_in[11];
  const float* Wd0=(const float*)d_in[12]; const float* bd0=(const float*)d_in[13];
  const float* W0b=(const float*)d_in[14]; const float* b0b=(const float*)d_in[15];
  const float* W1 =(const float*)d_in[16]; const float* b1 =(const float*)d_in[17];
  const float* Wd1=(const float*)d_in[18]; const float* bd1=(const float*)d_in[19];
  const float* W2 =(const float*)d_in[20]; const float* b2 =(const float*)d_in[21];
  const float* Wd2=(const float*)d_in[22]; const float* bd2=(const float*)d_in[23];
  const float* W3 =(const float*)d_in[24]; const float* b3 =(const float*)d_in[25];
  const float* Wd3=(const float*)d_in[26]; const float* bd3=(const float*)d_in[27];
  float* out = (float*)d_out;
  char* wsb = (char*)d_ws;

  size_t off = 0;
  auto alloc = [&](size_t nbytes){ size_t o = off; off += (nbytes + 255) & ~((size_t)255); return o; };
  size_t feats_o   = alloc((size_t)NPART*4*4);
  size_t bhfeats_o = alloc((size_t)NBHX*4*4);
  size_t rs_pp_o   = alloc(8256*4);
  size_t rs_bh_o   = alloc(8256*4);
  size_t gsrc_pp_o = alloc((size_t)EPX*4);
  size_t gbase_pp_o= alloc((size_t)EPX*4);
  size_t gw_pp_o   = alloc((size_t)EPX*8*4);
  size_t gsrc_bh_o = alloc((size_t)EBX*4);
  size_t gbase_bh_o= alloc((size_t)EBX*4);
  size_t gw_bh_o   = alloc((size_t)EBX*8*4);
  size_t hf_o  = alloc((size_t)NPART*96*4);
  size_t hb_o  = alloc((size_t)NPART*96*2);
  size_t h1f_o = alloc((size_t)NPART*64*4);
  size_t h1b_o = alloc((size_t)NPART*64*2);
  size_t h2f_o = alloc((size_t)NPART*64*4);
  size_t h2b_o = alloc((size_t)NPART*64*2);
  size_t bt1_o = alloc((size_t)4096*96*2);
  size_t bt2_o = alloc((size_t)4096*64*2);
  size_t bt3_o = alloc((size_t)256*64*2);
  size_t y0b_o = alloc((size_t)NBHX*64*32*2);
  size_t y_o   = alloc((size_t)NPART*4096*2);   // shared: Y0a / Y1 / Y2 / Y3

  float* featsP = (float*)(wsb + feats_o); float* bhfeatsP = (float*)(wsb + bhfeats_o);
  int* rsPP = (int*)(wsb + rs_pp_o); int* rsBH = (int*)(wsb + rs_bh_o);
  int* gsP = (int*)(wsb + gsrc_pp_o); int* gbP = (int*)(wsb + gbase_pp_o); float* gwP = (float*)(wsb + gw_pp_o);
  int* gsB = (int*)(wsb + gsrc_bh_o); int* gbB = (int*)(wsb + gbase_bh_o); float* gwB = (float*)(wsb + gw_bh_o);
  float* hf  = (float*)(wsb + hf_o);  unsigned short* hb  = (unsigned short*)(wsb + hb_o);
  float* h1f = (float*)(wsb + h1f_o); unsigned short* h1b = (unsigned short*)(wsb + h1b_o);
  float* h2f = (float*)(wsb + h2f_o); unsigned short* h2b = (unsigned short*)(wsb + h2b_o);
  unsigned short* BT1 = (unsigned short*)(wsb + bt1_o);
  unsigned short* BT2 = (unsigned short*)(wsb + bt2_o);
  unsigned short* BT3 = (unsigned short*)(wsb + bt3_o);
  unsigned short* Y0b = (unsigned short*)(wsb + y0b_o);
  unsigned short* Ybuf = (unsigned short*)(wsb + y_o);

  // ---- prep ----
  feats_kernel<<<(NPART+255)/256, 256, 0, stream>>>(vel, mass, bh_vel, bh_mass, featsP, bhfeatsP);
  geom_kernel<<<(EPX+255)/256, 256, 0, stream>>>(pos, pos, pp_src, pp_dst, EPX, NPART, 1.f/4.5f, gsP, gbP, gwP);
  geom_kernel<<<(EBX+255)/256, 256, 0, stream>>>(bh_pos, pos, bh_src, bh_dst, EBX, NPART, 1.f/18.f, gsB, gbB, gwB);
  csr_kernel<<<(NPART+1+255)/256, 256, 0, stream>>>(pp_dst, EPX, rsPP);
  csr_kernel<<<(NPART+1+255)/256, 256, 0, stream>>>(bh_dst, EBX, rsBH);
  wtransY_kernel<<<((size_t)4096*96+255)/256, 256, 0, stream>>>(W1, 96, 64, 64, BT1);
  wtransY_kernel<<<((size_t)4096*64+255)/256, 256, 0, stream>>>(W2, 64, 64, 64, BT2);
  wtransY_kernel<<<((size_t)256*64+255)/256, 256, 0, stream>>>(W3, 64, 3, 4, BT3);

  // ---- layer 0 ----
  y0_kernel<<<(NPART*256+255)/256, 256, 0, stream>>>(featsP, W0a, NPART, Ybuf);
  y0_kernel<<<(NBHX*256+255)/256, 256, 0, stream>>>(bhfeatsP, W0b, NBHX, Y0b);
  gather_l0_kernel<<<NPART/4, 256, 0, stream>>>(rsPP, gsP, gbP, gwP, rsBH, gsB, gbB, gwB,
                                                Ybuf, Y0b, featsP, Wd0, bd0, b0a, b0b, hf, hb);
  // ---- layer 1 ----
  {
    dim3 g(NPART/128, 4096/64);
    gemm_y_kernel<<<g, 256, 0, stream>>>(hb, BT1, 96, 4096, Ybuf);
    gather64_kernel<96,false><<<NPART/4, 256, 0, stream>>>(rsPP, gsP, gbP, gwP, Ybuf,
        hf, Wd1, bd1, b1, nullptr, h1f, h1b);
  }
  // ---- layer 2 ----
  {
    dim3 g(NPART/128, 4096/64);
    gemm_y_kernel<<<g, 256, 0, stream>>>(h1b, BT2, 64, 4096, Ybuf);
    gather64_kernel<64,true><<<NPART/4, 256, 0, stream>>>(rsPP, gsP, gbP, gwP, Ybuf,
        h1f, Wd2, bd2, b2, h1f, h2f, h2b);
  }
  // ---- layer 3 ----
  {
    dim3 g(NPART/128, 256/64);
    gemm_y_kernel<<<g, 256, 0, stream>>>(h2b, BT3, 64, 256, Ybuf);
    gather3_kernel<<<NPART/4, 256, 0, stream>>>(rsPP, gsP, gbP, gwP, Ybuf,
        h2f, Wd3, bd3, b3, out);
  }
}